// Round 1
// baseline (5658.331 us; speedup 1.0000x reference)
//
#include <hip/hip_runtime.h>
#include <math.h>

#define D_MODEL 256
#define NH 8
#define HD 32
#define NL 4
#define NP 4
#define DFF 1024
#define NLAYERS 6
#define BS 2
#define S_TOK 13294
#define MTOT (BS * S_TOK)   // 26588

// ---------------------------------------------------------------------------
// Reference points: rp[b,s,:] scaled by valid_ratios per target level.
// ---------------------------------------------------------------------------
__global__ void refpoints_kernel(const float* __restrict__ vr, float* __restrict__ ref)
{
    int t = blockIdx.x * blockDim.x + threadIdx.x;
    if (t >= MTOT) return;
    int b = t / S_TOK;
    int s = t - b * S_TOK;
    int lvl, W, H, start;
    if (s < 10000)      { lvl = 0; W = 100; H = 100; start = 0; }
    else if (s < 12500) { lvl = 1; W = 50;  H = 50;  start = 10000; }
    else if (s < 13125) { lvl = 2; W = 25;  H = 25;  start = 12500; }
    else                { lvl = 3; W = 13;  H = 13;  start = 13125; }
    int wi = s - start;
    int y = wi / W;
    int x = wi - y * W;
    float rx = (x + 0.5f) / (vr[(b * NL + lvl) * 2 + 0] * (float)W);
    float ry = (y + 0.5f) / (vr[(b * NL + lvl) * 2 + 1] * (float)H);
#pragma unroll
    for (int l2 = 0; l2 < NL; l2++) {
        ref[((size_t)t * NL + l2) * 2 + 0] = rx * vr[(b * NL + l2) * 2 + 0];
        ref[((size_t)t * NL + l2) * 2 + 1] = ry * vr[(b * NL + l2) * 2 + 1];
    }
}

// ---------------------------------------------------------------------------
// Tiled f32 GEMM: C[M,N] = (A (+A2))[M,K] @ B[K,N] + bias (+ optional ReLU)
// BM=128, BN=64, BK=16, 256 threads, 8x4 micro-tile per thread.
// N must be a multiple of 64, K a multiple of 16.
// ---------------------------------------------------------------------------
__global__ __launch_bounds__(256) void gemm_f32(
    const float* __restrict__ A, const float* __restrict__ A2,
    const float* __restrict__ B, const float* __restrict__ bias,
    float* __restrict__ C, int M, int N, int K, int relu)
{
    __shared__ float As[16][132];   // [k][m], padded
    __shared__ float Bs[16][68];    // [k][n], padded

    int tid = threadIdx.x;
    int m0 = blockIdx.y * 128;
    int n0 = blockIdx.x * 64;
    int r = tid >> 4;       // 0..15  -> row group (8 rows each)
    int c = tid & 15;       // 0..15  -> col group (4 cols each)

    float acc[8][4];
#pragma unroll
    for (int i = 0; i < 8; i++)
#pragma unroll
        for (int j = 0; j < 4; j++) acc[i][j] = 0.f;

    for (int k0 = 0; k0 < K; k0 += 16) {
        // A tile: 128 rows x 16 k = 512 float4, 2 per thread
#pragma unroll
        for (int i = 0; i < 2; i++) {
            int f = tid + i * 256;
            int row = f >> 2;
            int kp = (f & 3) * 4;
            float4 v = make_float4(0.f, 0.f, 0.f, 0.f);
            int gm = m0 + row;
            if (gm < M) {
                v = *(const float4*)(A + (size_t)gm * K + k0 + kp);
                if (A2) {
                    float4 w = *(const float4*)(A2 + (size_t)gm * K + k0 + kp);
                    v.x += w.x; v.y += w.y; v.z += w.z; v.w += w.w;
                }
            }
            As[kp + 0][row] = v.x;
            As[kp + 1][row] = v.y;
            As[kp + 2][row] = v.z;
            As[kp + 3][row] = v.w;
        }
        // B tile: 16 k x 64 n = 256 float4, 1 per thread
        {
            int trow = tid >> 4;
            int tcol = (tid & 15) * 4;
            float4 v = *(const float4*)(B + (size_t)(k0 + trow) * N + n0 + tcol);
            *(float4*)&Bs[trow][tcol] = v;
        }
        __syncthreads();
#pragma unroll
        for (int kk = 0; kk < 16; kk++) {
            float a[8], b[4];
#pragma unroll
            for (int i = 0; i < 8; i++) a[i] = As[kk][r * 8 + i];
#pragma unroll
            for (int j = 0; j < 4; j++) b[j] = Bs[kk][c * 4 + j];
#pragma unroll
            for (int i = 0; i < 8; i++)
#pragma unroll
                for (int j = 0; j < 4; j++)
                    acc[i][j] = fmaf(a[i], b[j], acc[i][j]);
        }
        __syncthreads();
    }

    float bv[4];
#pragma unroll
    for (int j = 0; j < 4; j++) bv[j] = bias[n0 + c * 4 + j];
#pragma unroll
    for (int i = 0; i < 8; i++) {
        int gm = m0 + r * 8 + i;
        if (gm < M) {
            float4 o;
            o.x = acc[i][0] + bv[0];
            o.y = acc[i][1] + bv[1];
            o.z = acc[i][2] + bv[2];
            o.w = acc[i][3] + bv[3];
            if (relu) {
                o.x = fmaxf(o.x, 0.f); o.y = fmaxf(o.y, 0.f);
                o.z = fmaxf(o.z, 0.f); o.w = fmaxf(o.w, 0.f);
            }
            *(float4*)(C + (size_t)gm * N + n0 + c * 4) = o;
        }
    }
}

// ---------------------------------------------------------------------------
// Softmax over the 16 (NL*NP) attention logits per (b,s,h), in place.
// ---------------------------------------------------------------------------
__global__ void softmax16_kernel(float* __restrict__ x, int total)
{
    int t = blockIdx.x * blockDim.x + threadIdx.x;
    if (t >= total) return;
    float* p = x + (size_t)t * 16;
    float v[16];
    float4 a0 = ((const float4*)p)[0];
    float4 a1 = ((const float4*)p)[1];
    float4 a2 = ((const float4*)p)[2];
    float4 a3 = ((const float4*)p)[3];
    v[0]=a0.x; v[1]=a0.y; v[2]=a0.z; v[3]=a0.w;
    v[4]=a1.x; v[5]=a1.y; v[6]=a1.z; v[7]=a1.w;
    v[8]=a2.x; v[9]=a2.y; v[10]=a2.z; v[11]=a2.w;
    v[12]=a3.x; v[13]=a3.y; v[14]=a3.z; v[15]=a3.w;
    float mx = v[0];
#pragma unroll
    for (int i = 1; i < 16; i++) mx = fmaxf(mx, v[i]);
    float s = 0.f;
#pragma unroll
    for (int i = 0; i < 16; i++) { v[i] = expf(v[i] - mx); s += v[i]; }
    float inv = 1.f / s;
#pragma unroll
    for (int i = 0; i < 16; i++) v[i] *= inv;
    float4 o0 = make_float4(v[0], v[1], v[2], v[3]);
    float4 o1 = make_float4(v[4], v[5], v[6], v[7]);
    float4 o2 = make_float4(v[8], v[9], v[10], v[11]);
    float4 o3 = make_float4(v[12], v[13], v[14], v[15]);
    ((float4*)p)[0] = o0; ((float4*)p)[1] = o1;
    ((float4*)p)[2] = o2; ((float4*)p)[3] = o3;
}

// ---------------------------------------------------------------------------
// Multi-scale deformable attention sampling.
// value  : [b, s, h, c]   (contiguous D = NH*HD)
// off    : [b, s, h, l, p, 2]
// attn   : [b, s, h, l*p]
// ref    : [b, s, l, 2]
// out    : [b, s, h, c]
// One thread per (b,s,h, 4-channel group): 8 threads per (b,s,h).
// ---------------------------------------------------------------------------
__global__ __launch_bounds__(256) void msdeform_kernel(
    const float* __restrict__ value, const float* __restrict__ off,
    const float* __restrict__ attn, const float* __restrict__ ref,
    float* __restrict__ out)
{
    const int total = MTOT * NH * (HD / 4);
    int t = blockIdx.x * blockDim.x + threadIdx.x;
    if (t >= total) return;
    int c4 = t & 7;          // channel group (4 floats)
    int h  = (t >> 3) & 7;
    int bs = t >> 6;         // b*S + s
    int b  = (bs >= S_TOK) ? 1 : 0;

    const int Ws[4] = {100, 50, 25, 13};
    const int Hs[4] = {100, 50, 25, 13};
    const int st[4] = {0, 10000, 12500, 13125};

    const float* offp = off  + ((size_t)bs * NH + h) * 32;
    const float* atp  = attn + ((size_t)bs * NH + h) * 16;
    const float* refp = ref  + (size_t)bs * NL * 2;

    float4 acc = make_float4(0.f, 0.f, 0.f, 0.f);

#pragma unroll
    for (int l = 0; l < NL; l++) {
        const int W = Ws[l], H = Hs[l], start = st[l];
        const float rx = refp[l * 2 + 0];
        const float ry = refp[l * 2 + 1];
        const float* vbase = value + (((size_t)b * S_TOK + start) * NH + h) * HD + c4 * 4;
        const float fW = (float)W, fH = (float)H;
#pragma unroll
        for (int p = 0; p < NP; p++) {
            float ox = offp[l * 8 + p * 2 + 0];
            float oy = offp[l * 8 + p * 2 + 1];
            float a  = atp[l * 4 + p];
            float lx = rx + ox / fW;
            float ly = ry + oy / fH;
            float x = lx * fW - 0.5f;
            float y = ly * fH - 0.5f;
            float x0f = floorf(x), y0f = floorf(y);
            float wx1 = x - x0f, wy1 = y - y0f;
            float wx0 = 1.f - wx1, wy0 = 1.f - wy1;
            int ix0 = (int)x0f, iy0 = (int)y0f;
#pragma unroll
            for (int dy = 0; dy < 2; dy++) {
                int yi = iy0 + dy;
                if (yi < 0 || yi >= H) continue;
                float wy = dy ? wy1 : wy0;
#pragma unroll
                for (int dx = 0; dx < 2; dx++) {
                    int xi = ix0 + dx;
                    if (xi < 0 || xi >= W) continue;
                    float wgt = (dx ? wx1 : wx0) * wy * a;
                    float4 g = *(const float4*)(vbase + (size_t)(yi * W + xi) * (NH * HD));
                    acc.x = fmaf(g.x, wgt, acc.x);
                    acc.y = fmaf(g.y, wgt, acc.y);
                    acc.z = fmaf(g.z, wgt, acc.z);
                    acc.w = fmaf(g.w, wgt, acc.w);
                }
            }
        }
    }
    *(float4*)(out + ((size_t)bs * NH + h) * HD + c4 * 4) = acc;
}

// ---------------------------------------------------------------------------
// out = LayerNorm(xres + x2) * g + be   (row width D=256, 1 wave per row)
// ---------------------------------------------------------------------------
__global__ __launch_bounds__(256) void add_ln_kernel(
    const float* __restrict__ xres, const float* __restrict__ x2,
    const float* __restrict__ g, const float* __restrict__ be,
    float* __restrict__ out)
{
    int row = blockIdx.x * 4 + (threadIdx.x >> 6);
    int lane = threadIdx.x & 63;
    if (row >= MTOT) return;
    float4 v = ((const float4*)(xres + (size_t)row * D_MODEL))[lane];
    float4 w = ((const float4*)(x2   + (size_t)row * D_MODEL))[lane];
    v.x += w.x; v.y += w.y; v.z += w.z; v.w += w.w;
    float sum = v.x + v.y + v.z + v.w;
    float sq  = v.x * v.x + v.y * v.y + v.z * v.z + v.w * v.w;
#pragma unroll
    for (int m = 32; m; m >>= 1) {
        sum += __shfl_xor(sum, m, 64);
        sq  += __shfl_xor(sq,  m, 64);
    }
    float mean = sum * (1.f / D_MODEL);
    float var  = sq * (1.f / D_MODEL) - mean * mean;
    float inv = rsqrtf(var + 1e-5f);
    int cb = lane * 4;
    float4 o;
    o.x = (v.x - mean) * inv * g[cb + 0] + be[cb + 0];
    o.y = (v.y - mean) * inv * g[cb + 1] + be[cb + 1];
    o.z = (v.z - mean) * inv * g[cb + 2] + be[cb + 2];
    o.w = (v.w - mean) * inv * g[cb + 3] + be[cb + 3];
    ((float4*)(out + (size_t)row * D_MODEL))[lane] = o;
}

// ---------------------------------------------------------------------------
extern "C" void kernel_launch(void* const* d_in, const int* in_sizes, int n_in,
                              void* d_out, int out_size, void* d_ws, size_t ws_size,
                              hipStream_t stream)
{
    const float* src    = (const float*)d_in[0];
    const float* pos    = (const float*)d_in[1];
    const float* vr     = (const float*)d_in[2];
    const float* W_off  = (const float*)d_in[3];
    const float* b_off  = (const float*)d_in[4];
    const float* W_attn = (const float*)d_in[5];
    const float* b_attn = (const float*)d_in[6];
    const float* W_val  = (const float*)d_in[7];
    const float* b_val  = (const float*)d_in[8];
    const float* W_out  = (const float*)d_in[9];
    const float* b_out  = (const float*)d_in[10];
    const float* g1     = (const float*)d_in[11];
    const float* be1    = (const float*)d_in[12];
    const float* W_ff1  = (const float*)d_in[13];
    const float* b_ff1  = (const float*)d_in[14];
    const float* W_ff2  = (const float*)d_in[15];
    const float* b_ff2  = (const float*)d_in[16];
    const float* g2     = (const float*)d_in[17];
    const float* be2    = (const float*)d_in[18];
    float* out = (float*)d_out;

    const size_t MS = (size_t)MTOT;
    float* w = (float*)d_ws;
    float* refb = w;  w += MS * NL * 2;       // 0.85 MB
    float* Xbuf = w;  w += MS * D_MODEL;      // 27.2 MB
    float* Ybuf = w;  w += MS * D_MODEL;
    float* valb = w;  w += MS * D_MODEL;      // value; later reused as ff2 out
    float* offb = w;  w += MS * D_MODEL;      // offsets; later reused as src2
    float* attb = w;  w += MS * 128;
    float* samb = w;  w += MS * D_MODEL;
    float* ffb  = w;  w += (size_t)8192 * DFF; // 33.5 MB ff1 chunk

    const int GY = (MTOT + 127) / 128;   // 208

    refpoints_kernel<<<(MTOT + 255) / 256, 256, 0, stream>>>(vr, refb);

    for (int l = 0; l < NLAYERS; l++) {
        const float* X = (l == 0) ? src : Xbuf;

        // value = X @ Wv + bv
        gemm_f32<<<dim3(4, GY), 256, 0, stream>>>(
            X, nullptr, W_val + (size_t)l * D_MODEL * D_MODEL, b_val + l * D_MODEL,
            valb, MTOT, D_MODEL, D_MODEL, 0);
        // off = (X+pos) @ Wo + bo
        gemm_f32<<<dim3(4, GY), 256, 0, stream>>>(
            X, pos, W_off + (size_t)l * D_MODEL * 256, b_off + l * 256,
            offb, MTOT, 256, D_MODEL, 0);
        // attn logits = (X+pos) @ Wa + ba
        gemm_f32<<<dim3(2, GY), 256, 0, stream>>>(
            X, pos, W_attn + (size_t)l * D_MODEL * 128, b_attn + l * 128,
            attb, MTOT, 128, D_MODEL, 0);
        softmax16_kernel<<<(MTOT * NH + 255) / 256, 256, 0, stream>>>(attb, MTOT * NH);
        msdeform_kernel<<<(MTOT * NH * 8 + 255) / 256, 256, 0, stream>>>(
            valb, offb, attb, refb, samb);
        // src2 = sampled @ W_out + b_out   (into offb, off no longer needed)
        gemm_f32<<<dim3(4, GY), 256, 0, stream>>>(
            samb, nullptr, W_out + (size_t)l * D_MODEL * D_MODEL, b_out + l * D_MODEL,
            offb, MTOT, D_MODEL, D_MODEL, 0);
        // Y = LN(X + src2)
        add_ln_kernel<<<MTOT / 4, 256, 0, stream>>>(X, offb, g1 + l * D_MODEL, be1 + l * D_MODEL, Ybuf);
        // FFN (chunked over rows to bound ff1 buffer)
        for (int r0 = 0; r0 < MTOT; r0 += 8192) {
            int mc = MTOT - r0 < 8192 ? MTOT - r0 : 8192;
            int gy = (mc + 127) / 128;
            gemm_f32<<<dim3(DFF / 64, gy), 256, 0, stream>>>(
                Ybuf + (size_t)r0 * D_MODEL, nullptr,
                W_ff1 + (size_t)l * D_MODEL * DFF, b_ff1 + l * DFF,
                ffb, mc, DFF, D_MODEL, 1);
            gemm_f32<<<dim3(4, gy), 256, 0, stream>>>(
                ffb, nullptr,
                W_ff2 + (size_t)l * DFF * D_MODEL, b_ff2 + l * D_MODEL,
                valb + (size_t)r0 * D_MODEL, mc, D_MODEL, DFF, 0);
        }
        // out = LN(Y + ff)
        float* dst = (l == NLAYERS - 1) ? out : Xbuf;
        add_ln_kernel<<<MTOT / 4, 256, 0, stream>>>(Ybuf, valb, g2 + l * D_MODEL, be2 + l * D_MODEL, dst);
    }
}

// Round 2
// 2519.869 us; speedup vs baseline: 2.2455x; 2.2455x over previous
//
#include <hip/hip_runtime.h>
#include <math.h>
#include <stdint.h>

#define D_MODEL 256
#define NH 8
#define HD 32
#define NL 4
#define NP 4
#define DFF 1024
#define NLAYERS 6
#define BS 2
#define S_TOK 13294
#define MTOT (BS * S_TOK)   // 26588
#define MPAD 26624          // 208 * 128

typedef unsigned short u16;
typedef __attribute__((ext_vector_type(8))) __bf16 bf16x8;
typedef __attribute__((ext_vector_type(4))) float f32x4;

__device__ inline u16 bf16_rne(float f) {
    union { float f; uint32_t u; } v; v.f = f;
    uint32_t u = v.u;
    return (u16)((u + 0x7FFFu + ((u >> 16) & 1u)) >> 16);
}

// ---------------------------------------------------------------------------
// Weight prep: all 6 layers' weights, f32 [K][N] -> bf16 [N][K] (transposed).
// Per-layer segment offsets (elements):
//   Wv 0..65536, Wo ..131072, Wa ..163840, Wout ..229376, Wf1 ..491520, Wf2 ..753664
// ---------------------------------------------------------------------------
#define WT_L 753664
#define WT_OV 0
#define WT_OO 65536
#define WT_OA 131072
#define WT_OOUT 163840
#define WT_OF1 229376
#define WT_OF2 491520

__global__ void wprep_kernel(const float* __restrict__ Wv, const float* __restrict__ Wo,
                             const float* __restrict__ Wa, const float* __restrict__ Wout,
                             const float* __restrict__ Wf1, const float* __restrict__ Wf2,
                             u16* __restrict__ dst)
{
    int idx = blockIdx.x * blockDim.x + threadIdx.x;
    if (idx >= NLAYERS * WT_L) return;
    int l = idx / WT_L;
    int r = idx - l * WT_L;
    const float* srcp; int N, K, sr;
    if (r < WT_OO)        { srcp = Wv   + (size_t)l * 65536;  N = 256;  K = 256;  sr = r - WT_OV; }
    else if (r < WT_OA)   { srcp = Wo   + (size_t)l * 65536;  N = 256;  K = 256;  sr = r - WT_OO; }
    else if (r < WT_OOUT) { srcp = Wa   + (size_t)l * 32768;  N = 128;  K = 256;  sr = r - WT_OA; }
    else if (r < WT_OF1)  { srcp = Wout + (size_t)l * 65536;  N = 256;  K = 256;  sr = r - WT_OOUT; }
    else if (r < WT_OF2)  { srcp = Wf1  + (size_t)l * 262144; N = 1024; K = 256;  sr = r - WT_OF1; }
    else                  { srcp = Wf2  + (size_t)l * 262144; N = 256;  K = 1024; sr = r - WT_OF2; }
    int n = sr / K, k = sr - n * K;
    dst[(size_t)l * WT_L + r] = bf16_rne(srcp[(size_t)k * N + n]);
}

// ---------------------------------------------------------------------------
// Reference points
// ---------------------------------------------------------------------------
__global__ void refpoints_kernel(const float* __restrict__ vr, float* __restrict__ ref)
{
    int t = blockIdx.x * blockDim.x + threadIdx.x;
    if (t >= MTOT) return;
    int b = t / S_TOK;
    int s = t - b * S_TOK;
    int lvl, W, H, start;
    if (s < 10000)      { lvl = 0; W = 100; H = 100; start = 0; }
    else if (s < 12500) { lvl = 1; W = 50;  H = 50;  start = 10000; }
    else if (s < 13125) { lvl = 2; W = 25;  H = 25;  start = 12500; }
    else                { lvl = 3; W = 13;  H = 13;  start = 13125; }
    int wi = s - start;
    int y = wi / W;
    int x = wi - y * W;
    float rx = (x + 0.5f) / (vr[(b * NL + lvl) * 2 + 0] * (float)W);
    float ry = (y + 0.5f) / (vr[(b * NL + lvl) * 2 + 1] * (float)H);
#pragma unroll
    for (int l2 = 0; l2 < NL; l2++) {
        ref[((size_t)t * NL + l2) * 2 + 0] = rx * vr[(b * NL + l2) * 2 + 0];
        ref[((size_t)t * NL + l2) * 2 + 1] = ry * vr[(b * NL + l2) * 2 + 1];
    }
}

// ---------------------------------------------------------------------------
// Initial conversion: Xb16 = bf16(src), Qb16 = bf16(src + pos)
// ---------------------------------------------------------------------------
__global__ void conv0_kernel(const float* __restrict__ src, const float* __restrict__ pos,
                             u16* __restrict__ Xb, u16* __restrict__ Qb)
{
    int t = blockIdx.x * blockDim.x + threadIdx.x;
    if (t >= MTOT * 64) return;
    float4 s = ((const float4*)src)[t];
    float4 p = ((const float4*)pos)[t];
    ushort4 a, q;
    a.x = bf16_rne(s.x); a.y = bf16_rne(s.y); a.z = bf16_rne(s.z); a.w = bf16_rne(s.w);
    q.x = bf16_rne(s.x + p.x); q.y = bf16_rne(s.y + p.y);
    q.z = bf16_rne(s.z + p.z); q.w = bf16_rne(s.w + p.w);
    ((ushort4*)Xb)[t] = a;
    ((ushort4*)Qb)[t] = q;
}

// ---------------------------------------------------------------------------
// BF16 MFMA GEMM (m97 structure): C[M,N] = A[M,K] @ Bt[N,K]^T + bias
// BM=BN=128, BK=32, 256 threads (4 waves, 2x2), acc 4x4 frags of 16x16x32.
// A is bf16 row-major (rows padded to tile grid), Bt is bf16 [N][K].
// ---------------------------------------------------------------------------
template<int RELU, int OUTBF16>
__global__ __launch_bounds__(256) void gemm_bf16(
    const u16* __restrict__ A, const u16* __restrict__ Bt,
    const float* __restrict__ bias, void* __restrict__ Cv,
    int Mguard, int N, int K)
{
    __shared__ __align__(16) u16 As[128 * 32];
    __shared__ __align__(16) u16 Bs[128 * 32];

    const int tid = threadIdx.x;
    const int wid = tid >> 6;
    const int lane = tid & 63;
    const int m0 = blockIdx.y * 128;
    const int n0 = blockIdx.x * 128;
    const int wr = wid >> 1, wc = wid & 1;

    f32x4 acc[4][4] = {};

    // staging coords: thread t loads 16B at (row = t>>2, chunk = t&3), twice (i: +64 rows)
    const u16* a0 = A + (size_t)(m0 + (tid >> 2)) * K + (tid & 3) * 8;
    const u16* b0 = Bt + (size_t)(n0 + (tid >> 2)) * K + (tid & 3) * 8;
    u16* asb = As + wid * 512;   // wave-uniform LDS base (bytes: wid*1024)
    u16* bsb = Bs + wid * 512;

    const int ko = (lane >> 4) * 8;
    const int rsel = lane & 15;

    for (int k0 = 0; k0 < K; k0 += 32) {
        __builtin_amdgcn_global_load_lds(
            (__attribute__((address_space(1))) void*)(a0 + k0),
            (__attribute__((address_space(3))) void*)(asb), 16, 0, 0);
        __builtin_amdgcn_global_load_lds(
            (__attribute__((address_space(1))) void*)(a0 + (size_t)64 * K + k0),
            (__attribute__((address_space(3))) void*)(asb + 2048), 16, 0, 0);
        __builtin_amdgcn_global_load_lds(
            (__attribute__((address_space(1))) void*)(b0 + k0),
            (__attribute__((address_space(3))) void*)(bsb), 16, 0, 0);
        __builtin_amdgcn_global_load_lds(
            (__attribute__((address_space(1))) void*)(b0 + (size_t)64 * K + k0),
            (__attribute__((address_space(3))) void*)(bsb + 2048), 16, 0, 0);
        __syncthreads();

        bf16x8 af[4], bfr[4];
#pragma unroll
        for (int i = 0; i < 4; i++) {
            af[i]  = *reinterpret_cast<const bf16x8*>(&As[(wr * 64 + i * 16 + rsel) * 32 + ko]);
            bfr[i] = *reinterpret_cast<const bf16x8*>(&Bs[(wc * 64 + i * 16 + rsel) * 32 + ko]);
        }
#pragma unroll
        for (int i = 0; i < 4; i++)
#pragma unroll
            for (int j = 0; j < 4; j++)
                acc[i][j] = __builtin_amdgcn_mfma_f32_16x16x32_bf16(af[i], bfr[j], acc[i][j], 0, 0, 0);
        __syncthreads();
    }

#pragma unroll
    for (int j = 0; j < 4; j++) {
        int col = n0 + wc * 64 + j * 16 + rsel;
        float bv = bias[col];
#pragma unroll
        for (int i = 0; i < 4; i++) {
            int rbase = m0 + wr * 64 + i * 16 + (lane >> 4) * 4;
#pragma unroll
            for (int r = 0; r < 4; r++) {
                int gm = rbase + r;
                if (gm < Mguard) {
                    float v = acc[i][j][r] + bv;
                    if (RELU) v = fmaxf(v, 0.f);
                    if (OUTBF16) ((u16*)Cv)[(size_t)gm * N + col] = bf16_rne(v);
                    else         ((float*)Cv)[(size_t)gm * N + col] = v;
                }
            }
        }
    }
}

// ---------------------------------------------------------------------------
// Softmax over 16 logits per (b,s,h), in place.
// ---------------------------------------------------------------------------
__global__ void softmax16_kernel(float* __restrict__ x, int total)
{
    int t = blockIdx.x * blockDim.x + threadIdx.x;
    if (t >= total) return;
    float* p = x + (size_t)t * 16;
    float v[16];
    float4 a0 = ((const float4*)p)[0];
    float4 a1 = ((const float4*)p)[1];
    float4 a2 = ((const float4*)p)[2];
    float4 a3 = ((const float4*)p)[3];
    v[0]=a0.x; v[1]=a0.y; v[2]=a0.z; v[3]=a0.w;
    v[4]=a1.x; v[5]=a1.y; v[6]=a1.z; v[7]=a1.w;
    v[8]=a2.x; v[9]=a2.y; v[10]=a2.z; v[11]=a2.w;
    v[12]=a3.x; v[13]=a3.y; v[14]=a3.z; v[15]=a3.w;
    float mx = v[0];
#pragma unroll
    for (int i = 1; i < 16; i++) mx = fmaxf(mx, v[i]);
    float s = 0.f;
#pragma unroll
    for (int i = 0; i < 16; i++) { v[i] = expf(v[i] - mx); s += v[i]; }
    float inv = 1.f / s;
#pragma unroll
    for (int i = 0; i < 16; i++) v[i] *= inv;
    ((float4*)p)[0] = make_float4(v[0], v[1], v[2], v[3]);
    ((float4*)p)[1] = make_float4(v[4], v[5], v[6], v[7]);
    ((float4*)p)[2] = make_float4(v[8], v[9], v[10], v[11]);
    ((float4*)p)[3] = make_float4(v[12], v[13], v[14], v[15]);
}

// ---------------------------------------------------------------------------
// Multi-scale deformable sampling; value f32, output bf16 (for W_out GEMM).
// ---------------------------------------------------------------------------
__global__ __launch_bounds__(256) void msdeform_kernel(
    const float* __restrict__ value, const float* __restrict__ off,
    const float* __restrict__ attn, const float* __restrict__ ref,
    u16* __restrict__ out)
{
    const int total = MTOT * NH * (HD / 4);
    int t = blockIdx.x * blockDim.x + threadIdx.x;
    if (t >= total) return;
    int c4 = t & 7;
    int h  = (t >> 3) & 7;
    int bs = t >> 6;
    int b  = (bs >= S_TOK) ? 1 : 0;

    const int Ws[4] = {100, 50, 25, 13};
    const int Hs[4] = {100, 50, 25, 13};
    const int st[4] = {0, 10000, 12500, 13125};

    const float* offp = off  + ((size_t)bs * NH + h) * 32;
    const float* atp  = attn + ((size_t)bs * NH + h) * 16;
    const float* refp = ref  + (size_t)bs * NL * 2;

    float4 acc = make_float4(0.f, 0.f, 0.f, 0.f);

#pragma unroll
    for (int l = 0; l < NL; l++) {
        const int W = Ws[l], H = Hs[l], start = st[l];
        const float rx = refp[l * 2 + 0];
        const float ry = refp[l * 2 + 1];
        const float* vbase = value + (((size_t)b * S_TOK + start) * NH + h) * HD + c4 * 4;
        const float fW = (float)W, fH = (float)H;
#pragma unroll
        for (int p = 0; p < NP; p++) {
            float ox = offp[l * 8 + p * 2 + 0];
            float oy = offp[l * 8 + p * 2 + 1];
            float a  = atp[l * 4 + p];
            float x = (rx + ox / fW) * fW - 0.5f;
            float y = (ry + oy / fH) * fH - 0.5f;
            float x0f = floorf(x), y0f = floorf(y);
            float wx1 = x - x0f, wy1 = y - y0f;
            float wx0 = 1.f - wx1, wy0 = 1.f - wy1;
            int ix0 = (int)x0f, iy0 = (int)y0f;
#pragma unroll
            for (int dy = 0; dy < 2; dy++) {
                int yi = iy0 + dy;
                if (yi < 0 || yi >= H) continue;
                float wy = dy ? wy1 : wy0;
#pragma unroll
                for (int dx = 0; dx < 2; dx++) {
                    int xi = ix0 + dx;
                    if (xi < 0 || xi >= W) continue;
                    float wgt = (dx ? wx1 : wx0) * wy * a;
                    float4 g = *(const float4*)(vbase + (size_t)(yi * W + xi) * D_MODEL);
                    acc.x = fmaf(g.x, wgt, acc.x);
                    acc.y = fmaf(g.y, wgt, acc.y);
                    acc.z = fmaf(g.z, wgt, acc.z);
                    acc.w = fmaf(g.w, wgt, acc.w);
                }
            }
        }
    }
    ushort4 o;
    o.x = bf16_rne(acc.x); o.y = bf16_rne(acc.y);
    o.z = bf16_rne(acc.z); o.w = bf16_rne(acc.w);
    *(ushort4*)(out + ((size_t)bs * NH + h) * HD + c4 * 4) = o;
}

// ---------------------------------------------------------------------------
// LN1: Y = LN(xres + x2); writes f32 Y and bf16 Y.
// ---------------------------------------------------------------------------
__global__ __launch_bounds__(256) void add_ln1_kernel(
    const float* __restrict__ xres, const float* __restrict__ x2,
    const float* __restrict__ g, const float* __restrict__ be,
    float* __restrict__ outf, u16* __restrict__ outb)
{
    int row = blockIdx.x * 4 + (threadIdx.x >> 6);
    int lane = threadIdx.x & 63;
    if (row >= MTOT) return;
    float4 v = ((const float4*)(xres + (size_t)row * D_MODEL))[lane];
    float4 w = ((const float4*)(x2   + (size_t)row * D_MODEL))[lane];
    v.x += w.x; v.y += w.y; v.z += w.z; v.w += w.w;
    float sum = v.x + v.y + v.z + v.w;
    float sq  = v.x * v.x + v.y * v.y + v.z * v.z + v.w * v.w;
#pragma unroll
    for (int m = 32; m; m >>= 1) { sum += __shfl_xor(sum, m, 64); sq += __shfl_xor(sq, m, 64); }
    float mean = sum * (1.f / D_MODEL);
    float var  = sq * (1.f / D_MODEL) - mean * mean;
    float inv = rsqrtf(var + 1e-5f);
    int cb = lane * 4;
    float4 o;
    o.x = (v.x - mean) * inv * g[cb + 0] + be[cb + 0];
    o.y = (v.y - mean) * inv * g[cb + 1] + be[cb + 1];
    o.z = (v.z - mean) * inv * g[cb + 2] + be[cb + 2];
    o.w = (v.w - mean) * inv * g[cb + 3] + be[cb + 3];
    ((float4*)(outf + (size_t)row * D_MODEL))[lane] = o;
    ushort4 ob;
    ob.x = bf16_rne(o.x); ob.y = bf16_rne(o.y); ob.z = bf16_rne(o.z); ob.w = bf16_rne(o.w);
    ((ushort4*)(outb + (size_t)row * D_MODEL))[lane] = ob;
}

// ---------------------------------------------------------------------------
// LN2: X' = LN(xres + x2); writes f32 X', bf16 X', bf16 (X'+pos).
// ---------------------------------------------------------------------------
__global__ __launch_bounds__(256) void add_ln2_kernel(
    const float* __restrict__ xres, const float* __restrict__ x2,
    const float* __restrict__ g, const float* __restrict__ be,
    const float* __restrict__ pos,
    float* __restrict__ outf, u16* __restrict__ outXb, u16* __restrict__ outQb)
{
    int row = blockIdx.x * 4 + (threadIdx.x >> 6);
    int lane = threadIdx.x & 63;
    if (row >= MTOT) return;
    float4 v = ((const float4*)(xres + (size_t)row * D_MODEL))[lane];
    float4 w = ((const float4*)(x2   + (size_t)row * D_MODEL))[lane];
    v.x += w.x; v.y += w.y; v.z += w.z; v.w += w.w;
    float sum = v.x + v.y + v.z + v.w;
    float sq  = v.x * v.x + v.y * v.y + v.z * v.z + v.w * v.w;
#pragma unroll
    for (int m = 32; m; m >>= 1) { sum += __shfl_xor(sum, m, 64); sq += __shfl_xor(sq, m, 64); }
    float mean = sum * (1.f / D_MODEL);
    float var  = sq * (1.f / D_MODEL) - mean * mean;
    float inv = rsqrtf(var + 1e-5f);
    int cb = lane * 4;
    float4 o;
    o.x = (v.x - mean) * inv * g[cb + 0] + be[cb + 0];
    o.y = (v.y - mean) * inv * g[cb + 1] + be[cb + 1];
    o.z = (v.z - mean) * inv * g[cb + 2] + be[cb + 2];
    o.w = (v.w - mean) * inv * g[cb + 3] + be[cb + 3];
    ((float4*)(outf + (size_t)row * D_MODEL))[lane] = o;
    ushort4 ob;
    ob.x = bf16_rne(o.x); ob.y = bf16_rne(o.y); ob.z = bf16_rne(o.z); ob.w = bf16_rne(o.w);
    ((ushort4*)(outXb + (size_t)row * D_MODEL))[lane] = ob;
    float4 p = ((const float4*)(pos + (size_t)row * D_MODEL))[lane];
    ushort4 qb;
    qb.x = bf16_rne(o.x + p.x); qb.y = bf16_rne(o.y + p.y);
    qb.z = bf16_rne(o.z + p.z); qb.w = bf16_rne(o.w + p.w);
    ((ushort4*)(outQb + (size_t)row * D_MODEL))[lane] = qb;
}

// ---------------------------------------------------------------------------
extern "C" void kernel_launch(void* const* d_in, const int* in_sizes, int n_in,
                              void* d_out, int out_size, void* d_ws, size_t ws_size,
                              hipStream_t stream)
{
    const float* src    = (const float*)d_in[0];
    const float* pos    = (const float*)d_in[1];
    const float* vr     = (const float*)d_in[2];
    const float* W_off  = (const float*)d_in[3];
    const float* b_off  = (const float*)d_in[4];
    const float* W_attn = (const float*)d_in[5];
    const float* b_attn = (const float*)d_in[6];
    const float* W_val  = (const float*)d_in[7];
    const float* b_val  = (const float*)d_in[8];
    const float* W_out  = (const float*)d_in[9];
    const float* b_out  = (const float*)d_in[10];
    const float* g1     = (const float*)d_in[11];
    const float* be1    = (const float*)d_in[12];
    const float* W_ff1  = (const float*)d_in[13];
    const float* b_ff1  = (const float*)d_in[14];
    const float* W_ff2  = (const float*)d_in[15];
    const float* b_ff2  = (const float*)d_in[16];
    const float* g2     = (const float*)d_in[17];
    const float* be2    = (const float*)d_in[18];
    float* out = (float*)d_out;

    uint8_t* wp = (uint8_t*)d_ws;
    auto alloc = [&](size_t bytes) { uint8_t* p = wp; wp += (bytes + 255) & ~(size_t)255; return p; };
    float* refb  = (float*)alloc((size_t)MTOT * 8 * 4);
    float* Xf    = (float*)alloc((size_t)MPAD * 256 * 4);
    float* Ybuf  = (float*)alloc((size_t)MPAD * 256 * 4);
    float* valb  = (float*)alloc((size_t)MPAD * 256 * 4);   // value; reused as ff2 out
    float* offb  = (float*)alloc((size_t)MPAD * 256 * 4);   // offsets; reused as src2
    uint8_t* slabA = alloc((size_t)8192 * 1024 * 2);        // attb (13.6MB) / ffb16 (16.8MB)
    uint8_t* slabB = alloc((size_t)MPAD * 256 * 2);         // Xb16 / samb16
    uint8_t* slabC = alloc((size_t)MPAD * 256 * 2);         // Qb16 / Yb16
    u16* Wt = (u16*)alloc((size_t)NLAYERS * WT_L * 2);      // 9.0MB bf16 transposed weights

    float* attb   = (float*)slabA;
    u16*   ffb16  = (u16*)slabA;
    u16*   Xb16   = (u16*)slabB;
    u16*   samb16 = (u16*)slabB;
    u16*   Qb16   = (u16*)slabC;
    u16*   Yb16   = (u16*)slabC;

    const int GY = MPAD / 128;   // 208

    wprep_kernel<<<(NLAYERS * WT_L + 255) / 256, 256, 0, stream>>>(
        W_val, W_off, W_attn, W_out, W_ff1, W_ff2, Wt);
    refpoints_kernel<<<(MTOT + 255) / 256, 256, 0, stream>>>(vr, refb);
    conv0_kernel<<<(MTOT * 64 + 255) / 256, 256, 0, stream>>>(src, pos, Xb16, Qb16);

    for (int l = 0; l < NLAYERS; l++) {
        const float* Xres = (l == 0) ? src : Xf;
        const u16* Wl = Wt + (size_t)l * WT_L;

        // value = X @ Wv + bv  (f32 out)
        gemm_bf16<0, 0><<<dim3(2, GY), 256, 0, stream>>>(
            Xb16, Wl + WT_OV, b_val + l * D_MODEL, valb, MTOT, 256, 256);
        // off = Q @ Wo + bo  (f32 out)
        gemm_bf16<0, 0><<<dim3(2, GY), 256, 0, stream>>>(
            Qb16, Wl + WT_OO, b_off + l * 256, offb, MTOT, 256, 256);
        // attn logits = Q @ Wa + ba  (f32 out, N=128)
        gemm_bf16<0, 0><<<dim3(1, GY), 256, 0, stream>>>(
            Qb16, Wl + WT_OA, b_attn + l * 128, attb, MTOT, 128, 256);
        softmax16_kernel<<<(MTOT * NH + 255) / 256, 256, 0, stream>>>(attb, MTOT * NH);
        // sampled (bf16 out into slabB; Xb16 dead)
        msdeform_kernel<<<(MTOT * NH * 8 + 255) / 256, 256, 0, stream>>>(
            valb, offb, attb, refb, samb16);
        // src2 = sampled @ W_out + b_out (into offb)
        gemm_bf16<0, 0><<<dim3(2, GY), 256, 0, stream>>>(
            samb16, Wl + WT_OOUT, b_out + l * D_MODEL, offb, MTOT, 256, 256);
        // Y = LN(X + src2): f32 + bf16 (Yb16 overwrites dead Qb16)
        add_ln1_kernel<<<MTOT / 4, 256, 0, stream>>>(
            Xres, offb, g1 + l * D_MODEL, be1 + l * D_MODEL, Ybuf, Yb16);
        // FFN, chunked over padded rows
        for (int r0 = 0; r0 < MPAD; r0 += 8192) {
            int rows = (MPAD - r0 < 8192) ? (MPAD - r0) : 8192;
            int valid = MTOT - r0; if (valid > rows) valid = rows;
            gemm_bf16<1, 1><<<dim3(8, rows / 128), 256, 0, stream>>>(
                Yb16 + (size_t)r0 * 256, Wl + WT_OF1, b_ff1 + l * DFF, ffb16, valid, 1024, 256);
            gemm_bf16<0, 0><<<dim3(2, rows / 128), 256, 0, stream>>>(
                ffb16, Wl + WT_OF2, b_ff2 + l * D_MODEL, valb + (size_t)r0 * 256, valid, 256, 1024);
        }
        // X' = LN(Y + ff): f32 (next residual or final out) + bf16 X' + bf16 (X'+pos)
        float* dst = (l == NLAYERS - 1) ? out : Xf;
        add_ln2_kernel<<<MTOT / 4, 256, 0, stream>>>(
            Ybuf, valb, g2 + l * D_MODEL, be2 + l * D_MODEL, pos, dst, Xb16, Qb16);
    }
}

// Round 3
// 1966.128 us; speedup vs baseline: 2.8779x; 1.2816x over previous
//
#include <hip/hip_runtime.h>
#include <math.h>
#include <stdint.h>

#define D_MODEL 256
#define NH 8
#define HD 32
#define NL 4
#define NP 4
#define DFF 1024
#define NLAYERS 6
#define BS 2
#define S_TOK 13294
#define MTOT (BS * S_TOK)   // 26588
#define MPAD 26624          // 208 * 128

typedef unsigned short u16;
typedef __attribute__((ext_vector_type(8))) __bf16 bf16x8;
typedef __attribute__((ext_vector_type(4))) float f32x4;

__device__ inline u16 bf16_rne(float f) {
    union { float f; uint32_t u; } v; v.f = f;
    uint32_t u = v.u;
    return (u16)((u + 0x7FFFu + ((u >> 16) & 1u)) >> 16);
}

// ---------------------------------------------------------------------------
// Weight prep: bf16, transposed to [N][K]. Per-layer segments (elements):
//   [OA: (Wo|Wa) 384*256][V: 256*256][OUT: 256*256][F1: 1024*256][F2: 256*1024]
// ---------------------------------------------------------------------------
#define WT_L 753664
#define WT_OA2 0
#define WT_OV 98304
#define WT_OOUT 163840
#define WT_OF1 229376
#define WT_OF2 491520

__global__ void wprep_kernel(const float* __restrict__ Wv, const float* __restrict__ Wo,
                             const float* __restrict__ Wa, const float* __restrict__ Wout,
                             const float* __restrict__ Wf1, const float* __restrict__ Wf2,
                             u16* __restrict__ dst)
{
    int idx = blockIdx.x * blockDim.x + threadIdx.x;
    if (idx >= NLAYERS * WT_L) return;
    int l = idx / WT_L;
    int r = idx - l * WT_L;
    float val;
    if (r < WT_OV) {                       // OA: cols 0-255 = Wo, 256-383 = Wa
        int n = r >> 8, k = r & 255;
        if (n < 256) val = Wo[(size_t)l * 65536 + k * 256 + n];
        else         val = Wa[(size_t)l * 32768 + k * 128 + (n - 256)];
    } else if (r < WT_OOUT) {
        int sr = r - WT_OV; int n = sr >> 8, k = sr & 255;
        val = Wv[(size_t)l * 65536 + k * 256 + n];
    } else if (r < WT_OF1) {
        int sr = r - WT_OOUT; int n = sr >> 8, k = sr & 255;
        val = Wout[(size_t)l * 65536 + k * 256 + n];
    } else if (r < WT_OF2) {
        int sr = r - WT_OF1; int n = sr >> 8, k = sr & 255;       // N=1024, K=256
        val = Wf1[(size_t)l * 262144 + k * 1024 + n];
    } else {
        int sr = r - WT_OF2; int n = sr >> 10, k = sr & 1023;     // N=256, K=1024
        val = Wf2[(size_t)l * 262144 + k * 256 + n];
    }
    dst[(size_t)l * WT_L + r] = bf16_rne(val);
}

// ---------------------------------------------------------------------------
__global__ void refpoints_kernel(const float* __restrict__ vr, float* __restrict__ ref)
{
    int t = blockIdx.x * blockDim.x + threadIdx.x;
    if (t >= MTOT) return;
    int b = t / S_TOK;
    int s = t - b * S_TOK;
    int lvl, W, H, start;
    if (s < 10000)      { lvl = 0; W = 100; H = 100; start = 0; }
    else if (s < 12500) { lvl = 1; W = 50;  H = 50;  start = 10000; }
    else if (s < 13125) { lvl = 2; W = 25;  H = 25;  start = 12500; }
    else                { lvl = 3; W = 13;  H = 13;  start = 13125; }
    int wi = s - start;
    int y = wi / W;
    int x = wi - y * W;
    float rx = (x + 0.5f) / (vr[(b * NL + lvl) * 2 + 0] * (float)W);
    float ry = (y + 0.5f) / (vr[(b * NL + lvl) * 2 + 1] * (float)H);
#pragma unroll
    for (int l2 = 0; l2 < NL; l2++) {
        ref[((size_t)t * NL + l2) * 2 + 0] = rx * vr[(b * NL + l2) * 2 + 0];
        ref[((size_t)t * NL + l2) * 2 + 1] = ry * vr[(b * NL + l2) * 2 + 1];
    }
}

// ---------------------------------------------------------------------------
__global__ void conv0_kernel(const float* __restrict__ src, const float* __restrict__ pos,
                             u16* __restrict__ Xb, u16* __restrict__ Qb)
{
    int t = blockIdx.x * blockDim.x + threadIdx.x;
    if (t >= MTOT * 64) return;
    float4 s = ((const float4*)src)[t];
    float4 p = ((const float4*)pos)[t];
    ushort4 a, q;
    a.x = bf16_rne(s.x); a.y = bf16_rne(s.y); a.z = bf16_rne(s.z); a.w = bf16_rne(s.w);
    q.x = bf16_rne(s.x + p.x); q.y = bf16_rne(s.y + p.y);
    q.z = bf16_rne(s.z + p.z); q.w = bf16_rne(s.w + p.w);
    ((ushort4*)Xb)[t] = a;
    ((ushort4*)Qb)[t] = q;
}

// ---------------------------------------------------------------------------
// BF16 MFMA GEMM: C[M,N] = A[M,K] @ Bt[N,K]^T + bias.
// MODE 0: f32 out. 1: bf16 out. 2: bf16+relu out.
// MODE 3: split — cols<256 -> f32 C (stride 256, bias), cols>=256 -> f32 C2
//         (stride 128, bias2). Block col-width 128 keeps dest uniform per block.
// ---------------------------------------------------------------------------
template<int MODE>
__global__ __launch_bounds__(256) void gemm_bf16(
    const u16* __restrict__ A, const u16* __restrict__ Bt,
    const float* __restrict__ bias, const float* __restrict__ bias2,
    void* __restrict__ Cv, void* __restrict__ C2v,
    int Mguard, int N, int K)
{
    __shared__ __align__(16) u16 As[128 * 32];
    __shared__ __align__(16) u16 Bs[128 * 32];

    const int tid = threadIdx.x;
    const int wid = tid >> 6;
    const int lane = tid & 63;
    const int m0 = blockIdx.y * 128;
    const int n0 = blockIdx.x * 128;
    const int wr = wid >> 1, wc = wid & 1;

    f32x4 acc[4][4] = {};

    const u16* a0 = A + (size_t)(m0 + (tid >> 2)) * K + (tid & 3) * 8;
    const u16* b0 = Bt + (size_t)(n0 + (tid >> 2)) * K + (tid & 3) * 8;
    u16* asb = As + wid * 512;
    u16* bsb = Bs + wid * 512;

    const int ko = (lane >> 4) * 8;
    const int rsel = lane & 15;

    for (int k0 = 0; k0 < K; k0 += 32) {
        __builtin_amdgcn_global_load_lds(
            (__attribute__((address_space(1))) void*)(a0 + k0),
            (__attribute__((address_space(3))) void*)(asb), 16, 0, 0);
        __builtin_amdgcn_global_load_lds(
            (__attribute__((address_space(1))) void*)(a0 + (size_t)64 * K + k0),
            (__attribute__((address_space(3))) void*)(asb + 2048), 16, 0, 0);
        __builtin_amdgcn_global_load_lds(
            (__attribute__((address_space(1))) void*)(b0 + k0),
            (__attribute__((address_space(3))) void*)(bsb), 16, 0, 0);
        __builtin_amdgcn_global_load_lds(
            (__attribute__((address_space(1))) void*)(b0 + (size_t)64 * K + k0),
            (__attribute__((address_space(3))) void*)(bsb + 2048), 16, 0, 0);
        __syncthreads();

        bf16x8 af[4], bfr[4];
#pragma unroll
        for (int i = 0; i < 4; i++) {
            af[i]  = *reinterpret_cast<const bf16x8*>(&As[(wr * 64 + i * 16 + rsel) * 32 + ko]);
            bfr[i] = *reinterpret_cast<const bf16x8*>(&Bs[(wc * 64 + i * 16 + rsel) * 32 + ko]);
        }
#pragma unroll
        for (int i = 0; i < 4; i++)
#pragma unroll
            for (int j = 0; j < 4; j++)
                acc[i][j] = __builtin_amdgcn_mfma_f32_16x16x32_bf16(af[i], bfr[j], acc[i][j], 0, 0, 0);
        __syncthreads();
    }

#pragma unroll
    for (int j = 0; j < 4; j++) {
        int col = n0 + wc * 64 + j * 16 + rsel;
        float bv = (MODE == 3) ? ((col < 256) ? bias[col] : bias2[col - 256]) : bias[col];
#pragma unroll
        for (int i = 0; i < 4; i++) {
            int rbase = m0 + wr * 64 + i * 16 + (lane >> 4) * 4;
#pragma unroll
            for (int r = 0; r < 4; r++) {
                int gm = rbase + r;
                if (gm < Mguard) {
                    float v = acc[i][j][r] + bv;
                    if (MODE == 2) v = fmaxf(v, 0.f);
                    if (MODE == 0) ((float*)Cv)[(size_t)gm * N + col] = v;
                    else if (MODE == 1 || MODE == 2) ((u16*)Cv)[(size_t)gm * N + col] = bf16_rne(v);
                    else {
                        if (col < 256) ((float*)Cv)[(size_t)gm * 256 + col] = v;
                        else           ((float*)C2v)[(size_t)gm * 128 + col - 256] = v;
                    }
                }
            }
        }
    }
}

// ---------------------------------------------------------------------------
__global__ void softmax16_kernel(float* __restrict__ x, int total)
{
    int t = blockIdx.x * blockDim.x + threadIdx.x;
    if (t >= total) return;
    float* p = x + (size_t)t * 16;
    float v[16];
    float4 a0 = ((const float4*)p)[0];
    float4 a1 = ((const float4*)p)[1];
    float4 a2 = ((const float4*)p)[2];
    float4 a3 = ((const float4*)p)[3];
    v[0]=a0.x; v[1]=a0.y; v[2]=a0.z; v[3]=a0.w;
    v[4]=a1.x; v[5]=a1.y; v[6]=a1.z; v[7]=a1.w;
    v[8]=a2.x; v[9]=a2.y; v[10]=a2.z; v[11]=a2.w;
    v[12]=a3.x; v[13]=a3.y; v[14]=a3.z; v[15]=a3.w;
    float mx = v[0];
#pragma unroll
    for (int i = 1; i < 16; i++) mx = fmaxf(mx, v[i]);
    float s = 0.f;
#pragma unroll
    for (int i = 0; i < 16; i++) { v[i] = expf(v[i] - mx); s += v[i]; }
    float inv = 1.f / s;
#pragma unroll
    for (int i = 0; i < 16; i++) v[i] *= inv;
    ((float4*)p)[0] = make_float4(v[0], v[1], v[2], v[3]);
    ((float4*)p)[1] = make_float4(v[4], v[5], v[6], v[7]);
    ((float4*)p)[2] = make_float4(v[8], v[9], v[10], v[11]);
    ((float4*)p)[3] = make_float4(v[12], v[13], v[14], v[15]);
}

// ---------------------------------------------------------------------------
// Multi-scale deformable sampling; value bf16, 4 threads per (b,s,h),
// each handling 8 channels (one 16B gather per corner). Output bf16.
// ---------------------------------------------------------------------------
__global__ __launch_bounds__(256) void msdeform_kernel(
    const u16* __restrict__ value, const float* __restrict__ off,
    const float* __restrict__ attn, const float* __restrict__ ref,
    u16* __restrict__ out)
{
    const int total = MTOT * NH * 4;
    int t = blockIdx.x * blockDim.x + threadIdx.x;
    if (t >= total) return;
    int c8 = t & 3;          // 8-channel group
    int h  = (t >> 2) & 7;
    int bs = t >> 5;
    int b  = (bs >= S_TOK) ? 1 : 0;

    const int Ws[4] = {100, 50, 25, 13};
    const int Hs[4] = {100, 50, 25, 13};
    const int st[4] = {0, 10000, 12500, 13125};

    const float* offp = off  + ((size_t)bs * NH + h) * 32;
    const float* atp  = attn + ((size_t)bs * NH + h) * 16;
    const float* refp = ref  + (size_t)bs * NL * 2;

    float acc[8] = {};

#pragma unroll
    for (int l = 0; l < NL; l++) {
        const int W = Ws[l], H = Hs[l];
        const u16* vbase = value + ((size_t)b * S_TOK + st[l]) * D_MODEL + h * HD + c8 * 8;
        const float rx = refp[l * 2 + 0];
        const float ry = refp[l * 2 + 1];
        const float fW = (float)W, fH = (float)H;
#pragma unroll
        for (int p = 0; p < NP; p++) {
            float x = (rx + offp[l * 8 + p * 2 + 0] / fW) * fW - 0.5f;
            float y = (ry + offp[l * 8 + p * 2 + 1] / fH) * fH - 0.5f;
            float a = atp[l * 4 + p];
            float x0f = floorf(x), y0f = floorf(y);
            float wx1 = x - x0f, wy1 = y - y0f;
            float wx0 = 1.f - wx1, wy0 = 1.f - wy1;
            int ix0 = (int)x0f, iy0 = (int)y0f;
#pragma unroll
            for (int dy = 0; dy < 2; dy++) {
                int yi = iy0 + dy;
                if (yi < 0 || yi >= H) continue;
                float wy = dy ? wy1 : wy0;
#pragma unroll
                for (int dx = 0; dx < 2; dx++) {
                    int xi = ix0 + dx;
                    if (xi < 0 || xi >= W) continue;
                    float wgt = (dx ? wx1 : wx0) * wy * a;
                    uint4 gv = *(const uint4*)(vbase + (size_t)(yi * W + xi) * D_MODEL);
                    union { uint32_t q; float f; } lo, hi;
                    lo.q = gv.x << 16; hi.q = gv.x & 0xffff0000u;
                    acc[0] = fmaf(lo.f, wgt, acc[0]); acc[1] = fmaf(hi.f, wgt, acc[1]);
                    lo.q = gv.y << 16; hi.q = gv.y & 0xffff0000u;
                    acc[2] = fmaf(lo.f, wgt, acc[2]); acc[3] = fmaf(hi.f, wgt, acc[3]);
                    lo.q = gv.z << 16; hi.q = gv.z & 0xffff0000u;
                    acc[4] = fmaf(lo.f, wgt, acc[4]); acc[5] = fmaf(hi.f, wgt, acc[5]);
                    lo.q = gv.w << 16; hi.q = gv.w & 0xffff0000u;
                    acc[6] = fmaf(lo.f, wgt, acc[6]); acc[7] = fmaf(hi.f, wgt, acc[7]);
                }
            }
        }
    }
    uint4 o;
    o.x = ((uint32_t)bf16_rne(acc[1]) << 16) | bf16_rne(acc[0]);
    o.y = ((uint32_t)bf16_rne(acc[3]) << 16) | bf16_rne(acc[2]);
    o.z = ((uint32_t)bf16_rne(acc[5]) << 16) | bf16_rne(acc[4]);
    o.w = ((uint32_t)bf16_rne(acc[7]) << 16) | bf16_rne(acc[6]);
    ((uint4*)out)[((size_t)bs * NH + h) * 4 + c8] = o;
}

// ---------------------------------------------------------------------------
__global__ __launch_bounds__(256) void add_ln1_kernel(
    const float* __restrict__ xres, const float* __restrict__ x2,
    const float* __restrict__ g, const float* __restrict__ be,
    float* __restrict__ outf, u16* __restrict__ outb)
{
    int row = blockIdx.x * 4 + (threadIdx.x >> 6);
    int lane = threadIdx.x & 63;
    if (row >= MTOT) return;
    float4 v = ((const float4*)(xres + (size_t)row * D_MODEL))[lane];
    float4 w = ((const float4*)(x2   + (size_t)row * D_MODEL))[lane];
    v.x += w.x; v.y += w.y; v.z += w.z; v.w += w.w;
    float sum = v.x + v.y + v.z + v.w;
    float sq  = v.x * v.x + v.y * v.y + v.z * v.z + v.w * v.w;
#pragma unroll
    for (int m = 32; m; m >>= 1) { sum += __shfl_xor(sum, m, 64); sq += __shfl_xor(sq, m, 64); }
    float mean = sum * (1.f / D_MODEL);
    float var  = sq * (1.f / D_MODEL) - mean * mean;
    float inv = rsqrtf(var + 1e-5f);
    int cb = lane * 4;
    float4 o;
    o.x = (v.x - mean) * inv * g[cb + 0] + be[cb + 0];
    o.y = (v.y - mean) * inv * g[cb + 1] + be[cb + 1];
    o.z = (v.z - mean) * inv * g[cb + 2] + be[cb + 2];
    o.w = (v.w - mean) * inv * g[cb + 3] + be[cb + 3];
    ((float4*)(outf + (size_t)row * D_MODEL))[lane] = o;
    ushort4 ob;
    ob.x = bf16_rne(o.x); ob.y = bf16_rne(o.y); ob.z = bf16_rne(o.z); ob.w = bf16_rne(o.w);
    ((ushort4*)(outb + (size_t)row * D_MODEL))[lane] = ob;
}

__global__ __launch_bounds__(256) void add_ln2_kernel(
    const float* __restrict__ xres, const float* __restrict__ x2,
    const float* __restrict__ g, const float* __restrict__ be,
    const float* __restrict__ pos,
    float* __restrict__ outf, u16* __restrict__ outXb, u16* __restrict__ outQb)
{
    int row = blockIdx.x * 4 + (threadIdx.x >> 6);
    int lane = threadIdx.x & 63;
    if (row >= MTOT) return;
    float4 v = ((const float4*)(xres + (size_t)row * D_MODEL))[lane];
    float4 w = ((const float4*)(x2   + (size_t)row * D_MODEL))[lane];
    v.x += w.x; v.y += w.y; v.z += w.z; v.w += w.w;
    float sum = v.x + v.y + v.z + v.w;
    float sq  = v.x * v.x + v.y * v.y + v.z * v.z + v.w * v.w;
#pragma unroll
    for (int m = 32; m; m >>= 1) { sum += __shfl_xor(sum, m, 64); sq += __shfl_xor(sq, m, 64); }
    float mean = sum * (1.f / D_MODEL);
    float var  = sq * (1.f / D_MODEL) - mean * mean;
    float inv = rsqrtf(var + 1e-5f);
    int cb = lane * 4;
    float4 o;
    o.x = (v.x - mean) * inv * g[cb + 0] + be[cb + 0];
    o.y = (v.y - mean) * inv * g[cb + 1] + be[cb + 1];
    o.z = (v.z - mean) * inv * g[cb + 2] + be[cb + 2];
    o.w = (v.w - mean) * inv * g[cb + 3] + be[cb + 3];
    ((float4*)(outf + (size_t)row * D_MODEL))[lane] = o;
    ushort4 ob;
    ob.x = bf16_rne(o.x); ob.y = bf16_rne(o.y); ob.z = bf16_rne(o.z); ob.w = bf16_rne(o.w);
    ((ushort4*)(outXb + (size_t)row * D_MODEL))[lane] = ob;
    float4 p = ((const float4*)(pos + (size_t)row * D_MODEL))[lane];
    ushort4 qb;
    qb.x = bf16_rne(o.x + p.x); qb.y = bf16_rne(o.y + p.y);
    qb.z = bf16_rne(o.z + p.z); qb.w = bf16_rne(o.w + p.w);
    ((ushort4*)(outQb + (size_t)row * D_MODEL))[lane] = qb;
}

// ---------------------------------------------------------------------------
extern "C" void kernel_launch(void* const* d_in, const int* in_sizes, int n_in,
                              void* d_out, int out_size, void* d_ws, size_t ws_size,
                              hipStream_t stream)
{
    const float* src    = (const float*)d_in[0];
    const float* pos    = (const float*)d_in[1];
    const float* vr     = (const float*)d_in[2];
    const float* W_off  = (const float*)d_in[3];
    const float* b_off  = (const float*)d_in[4];
    const float* W_attn = (const float*)d_in[5];
    const float* b_attn = (const float*)d_in[6];
    const float* W_val  = (const float*)d_in[7];
    const float* b_val  = (const float*)d_in[8];
    const float* W_out  = (const float*)d_in[9];
    const float* b_out  = (const float*)d_in[10];
    const float* g1     = (const float*)d_in[11];
    const float* be1    = (const float*)d_in[12];
    const float* W_ff1  = (const float*)d_in[13];
    const float* b_ff1  = (const float*)d_in[14];
    const float* W_ff2  = (const float*)d_in[15];
    const float* b_ff2  = (const float*)d_in[16];
    const float* g2     = (const float*)d_in[17];
    const float* be2    = (const float*)d_in[18];
    float* out = (float*)d_out;

    uint8_t* wp = (uint8_t*)d_ws;
    auto alloc = [&](size_t bytes) { uint8_t* p = wp; wp += (bytes + 255) & ~(size_t)255; return p; };
    float* refb   = (float*)alloc((size_t)MTOT * 8 * 4);
    float* Ybuf   = (float*)alloc((size_t)MPAD * 256 * 4);
    float* Xf     = (float*)alloc((size_t)MPAD * 256 * 4);  // dead during FFN -> aliased by ffb16
    float* offb   = (float*)alloc((size_t)MPAD * 256 * 4);  // off -> src2 -> ff2 out
    float* attb   = (float*)alloc((size_t)MPAD * 128 * 4);
    u16*   valb16 = (u16*)alloc((size_t)MPAD * 256 * 2);
    uint8_t* slabB = alloc((size_t)MPAD * 256 * 2);         // Xb16 / samb16
    uint8_t* slabC = alloc((size_t)MPAD * 256 * 2);         // Qb16 / Yb16
    u16* Wt = (u16*)alloc((size_t)NLAYERS * WT_L * 2);

    u16* Xb16   = (u16*)slabB;
    u16* samb16 = (u16*)slabB;
    u16* Qb16   = (u16*)slabC;
    u16* Yb16   = (u16*)slabC;
    u16* ffb16  = (u16*)Xf;   // 13312*1024*2 == MPAD*256*4 bytes exactly

    const int GY = MPAD / 128;   // 208
    const int CHUNK = 13312;     // 104 * 128

    wprep_kernel<<<(NLAYERS * WT_L + 255) / 256, 256, 0, stream>>>(
        W_val, W_off, W_attn, W_out, W_ff1, W_ff2, Wt);
    refpoints_kernel<<<(MTOT + 255) / 256, 256, 0, stream>>>(vr, refb);
    conv0_kernel<<<(MTOT * 64 + 255) / 256, 256, 0, stream>>>(src, pos, Xb16, Qb16);

    for (int l = 0; l < NLAYERS; l++) {
        const float* Xres = (l == 0) ? src : Xf;
        const u16* Wl = Wt + (size_t)l * WT_L;

        // off|attn = Q @ [Wo|Wa] + [bo|ba]   (split f32 out)
        gemm_bf16<3><<<dim3(3, GY), 256, 0, stream>>>(
            Qb16, Wl + WT_OA2, b_off + l * 256, b_attn + l * 128, offb, attb, MTOT, 384, 256);
        // value = X @ Wv + bv  (bf16 out)
        gemm_bf16<1><<<dim3(2, GY), 256, 0, stream>>>(
            Xb16, Wl + WT_OV, b_val + l * D_MODEL, nullptr, valb16, nullptr, MTOT, 256, 256);
        softmax16_kernel<<<(MTOT * NH + 255) / 256, 256, 0, stream>>>(attb, MTOT * NH);
        // sampled -> samb16 (overwrites dead Xb16)
        msdeform_kernel<<<(MTOT * NH * 4 + 255) / 256, 256, 0, stream>>>(
            valb16, offb, attb, refb, samb16);
        // src2 = sampled @ W_out + b_out -> offb (off values dead)
        gemm_bf16<0><<<dim3(2, GY), 256, 0, stream>>>(
            samb16, Wl + WT_OOUT, b_out + l * D_MODEL, nullptr, offb, nullptr, MTOT, 256, 256);
        // Y = LN(X + src2) -> Ybuf f32, Yb16 (overwrites dead Qb16)
        add_ln1_kernel<<<MTOT / 4, 256, 0, stream>>>(
            Xres, offb, g1 + l * D_MODEL, be1 + l * D_MODEL, Ybuf, Yb16);
        // FFN: 2 chunks; ff1 bf16+relu into ffb16 (aliases dead Xf), ff2 f32 into offb
        for (int r0 = 0; r0 < MPAD; r0 += CHUNK) {
            int valid = MTOT - r0; if (valid > CHUNK) valid = CHUNK;
            gemm_bf16<2><<<dim3(8, CHUNK / 128), 256, 0, stream>>>(
                Yb16 + (size_t)r0 * 256, Wl + WT_OF1, b_ff1 + l * DFF, nullptr,
                ffb16, nullptr, valid, 1024, 256);
            gemm_bf16<0><<<dim3(2, CHUNK / 128), 256, 0, stream>>>(
                ffb16, Wl + WT_OF2, b_ff2 + l * D_MODEL, nullptr,
                offb + (size_t)r0 * 256, nullptr, valid, 256, 1024);
        }
        // X' = LN(Y + ff) -> dst f32, bf16 X', bf16 (X'+pos)
        float* dst = (l == NLAYERS - 1) ? out : Xf;
        add_ln2_kernel<<<MTOT / 4, 256, 0, stream>>>(
            Ybuf, offb, g2 + l * D_MODEL, be2 + l * D_MODEL, pos, dst, Xb16, Qb16);
    }
}

// Round 4
// 1382.559 us; speedup vs baseline: 4.0926x; 1.4221x over previous
//
#include <hip/hip_runtime.h>
#include <math.h>
#include <stdint.h>

#define D_MODEL 256
#define NH 8
#define HD 32
#define NL 4
#define NP 4
#define DFF 1024
#define NLAYERS 6
#define BS 2
#define S_TOK 13294
#define MTOT (BS * S_TOK)   // 26588
#define MPAD 26624          // 208 * 128

typedef unsigned short u16;
typedef __attribute__((ext_vector_type(8))) __bf16 bf16x8;
typedef __attribute__((ext_vector_type(4))) float f32x4;

__device__ inline u16 bf16_rne(float f) {
    union { float f; uint32_t u; } v; v.f = f;
    uint32_t u = v.u;
    return (u16)((u + 0x7FFFu + ((u >> 16) & 1u)) >> 16);
}

// ---------------------------------------------------------------------------
// Weight prep: bf16, transposed to [N][K]. Per-layer segments (elements):
//   [OA: (Wo|Wa) 384*256][V: 256*256][OUT: 256*256][F1: 1024*256][F2: 256*1024]
// ---------------------------------------------------------------------------
#define WT_L 753664
#define WT_OA2 0
#define WT_OV 98304
#define WT_OOUT 163840
#define WT_OF1 229376
#define WT_OF2 491520

__global__ void wprep_kernel(const float* __restrict__ Wv, const float* __restrict__ Wo,
                             const float* __restrict__ Wa, const float* __restrict__ Wout,
                             const float* __restrict__ Wf1, const float* __restrict__ Wf2,
                             u16* __restrict__ dst)
{
    int idx = blockIdx.x * blockDim.x + threadIdx.x;
    if (idx >= NLAYERS * WT_L) return;
    int l = idx / WT_L;
    int r = idx - l * WT_L;
    float val;
    if (r < WT_OV) {                       // OA: cols 0-255 = Wo, 256-383 = Wa
        int n = r >> 8, k = r & 255;
        if (n < 256) val = Wo[(size_t)l * 65536 + k * 256 + n];
        else         val = Wa[(size_t)l * 32768 + k * 128 + (n - 256)];
    } else if (r < WT_OOUT) {
        int sr = r - WT_OV; int n = sr >> 8, k = sr & 255;
        val = Wv[(size_t)l * 65536 + k * 256 + n];
    } else if (r < WT_OF1) {
        int sr = r - WT_OOUT; int n = sr >> 8, k = sr & 255;
        val = Wout[(size_t)l * 65536 + k * 256 + n];
    } else if (r < WT_OF2) {
        int sr = r - WT_OF1; int n = sr >> 8, k = sr & 255;       // N=1024, K=256
        val = Wf1[(size_t)l * 262144 + k * 1024 + n];
    } else {
        int sr = r - WT_OF2; int n = sr >> 10, k = sr & 1023;     // N=256, K=1024
        val = Wf2[(size_t)l * 262144 + k * 256 + n];
    }
    dst[(size_t)l * WT_L + r] = bf16_rne(val);
}

// ---------------------------------------------------------------------------
__global__ void refpoints_kernel(const float* __restrict__ vr, float* __restrict__ ref)
{
    int t = blockIdx.x * blockDim.x + threadIdx.x;
    if (t >= MTOT) return;
    int b = t / S_TOK;
    int s = t - b * S_TOK;
    int lvl, W, H, start;
    if (s < 10000)      { lvl = 0; W = 100; H = 100; start = 0; }
    else if (s < 12500) { lvl = 1; W = 50;  H = 50;  start = 10000; }
    else if (s < 13125) { lvl = 2; W = 25;  H = 25;  start = 12500; }
    else                { lvl = 3; W = 13;  H = 13;  start = 13125; }
    int wi = s - start;
    int y = wi / W;
    int x = wi - y * W;
    float rx = (x + 0.5f) / (vr[(b * NL + lvl) * 2 + 0] * (float)W);
    float ry = (y + 0.5f) / (vr[(b * NL + lvl) * 2 + 1] * (float)H);
#pragma unroll
    for (int l2 = 0; l2 < NL; l2++) {
        ref[((size_t)t * NL + l2) * 2 + 0] = rx * vr[(b * NL + l2) * 2 + 0];
        ref[((size_t)t * NL + l2) * 2 + 1] = ry * vr[(b * NL + l2) * 2 + 1];
    }
}

// ---------------------------------------------------------------------------
__global__ void conv0_kernel(const float* __restrict__ src, const float* __restrict__ pos,
                             u16* __restrict__ Xb, u16* __restrict__ Qb)
{
    int t = blockIdx.x * blockDim.x + threadIdx.x;
    if (t >= MTOT * 64) return;
    float4 s = ((const float4*)src)[t];
    float4 p = ((const float4*)pos)[t];
    ushort4 a, q;
    a.x = bf16_rne(s.x); a.y = bf16_rne(s.y); a.z = bf16_rne(s.z); a.w = bf16_rne(s.w);
    q.x = bf16_rne(s.x + p.x); q.y = bf16_rne(s.y + p.y);
    q.z = bf16_rne(s.z + p.z); q.w = bf16_rne(s.w + p.w);
    ((ushort4*)Xb)[t] = a;
    ((ushort4*)Qb)[t] = q;
}

// ---------------------------------------------------------------------------
// BF16 MFMA GEMM: C[M,N] = A[M,K] @ Bt[N,K]^T + bias.
// All destinations are MPAD-row-padded workspace buffers -> no M guard.
// MODE 0: f32 out. 1: bf16 out. 2: bf16+relu out.
// MODE 3: split — block-uniform: n0<256 -> f32 Cv (stride 256, bias),
//         n0>=256 -> f32 C2v (stride 128, bias2).
// XCD-chunk block swizzle (bijective, m204) for A-panel L2 locality.
// ---------------------------------------------------------------------------
template<int MODE>
__global__ __launch_bounds__(256) void gemm_bf16(
    const u16* __restrict__ A, const u16* __restrict__ Bt,
    const float* __restrict__ bias, const float* __restrict__ bias2,
    void* __restrict__ Cv, void* __restrict__ C2v,
    int N, int K)
{
    __shared__ __align__(16) u16 As[128 * 32];
    __shared__ __align__(16) u16 Bs[128 * 32];

    const int tid = threadIdx.x;
    const int wid = tid >> 6;
    const int lane = tid & 63;

    const int nwg = gridDim.x * gridDim.y;
    const int bid = blockIdx.y * gridDim.x + blockIdx.x;
    const int q = nwg >> 3, rr = nwg & 7;
    const int xcd = bid & 7, cidx = bid >> 3;
    const int wg = (xcd < rr ? xcd * (q + 1) : rr * (q + 1) + (xcd - rr) * q) + cidx;
    const int m0 = (wg / gridDim.x) * 128;
    const int n0 = (wg % gridDim.x) * 128;
    const int wr = wid >> 1, wc = wid & 1;

    f32x4 acc[4][4] = {};

    const u16* a0 = A + (size_t)(m0 + (tid >> 2)) * K + (tid & 3) * 8;
    const u16* b0 = Bt + (size_t)(n0 + (tid >> 2)) * K + (tid & 3) * 8;
    u16* asb = As + wid * 512;
    u16* bsb = Bs + wid * 512;

    const int ko = (lane >> 4) * 8;
    const int rsel = lane & 15;

    for (int k0 = 0; k0 < K; k0 += 32) {
        __builtin_amdgcn_global_load_lds(
            (__attribute__((address_space(1))) void*)(a0 + k0),
            (__attribute__((address_space(3))) void*)(asb), 16, 0, 0);
        __builtin_amdgcn_global_load_lds(
            (__attribute__((address_space(1))) void*)(a0 + (size_t)64 * K + k0),
            (__attribute__((address_space(3))) void*)(asb + 2048), 16, 0, 0);
        __builtin_amdgcn_global_load_lds(
            (__attribute__((address_space(1))) void*)(b0 + k0),
            (__attribute__((address_space(3))) void*)(bsb), 16, 0, 0);
        __builtin_amdgcn_global_load_lds(
            (__attribute__((address_space(1))) void*)(b0 + (size_t)64 * K + k0),
            (__attribute__((address_space(3))) void*)(bsb + 2048), 16, 0, 0);
        __syncthreads();

        bf16x8 af[4], bfr[4];
#pragma unroll
        for (int i = 0; i < 4; i++) {
            af[i]  = *reinterpret_cast<const bf16x8*>(&As[(wr * 64 + i * 16 + rsel) * 32 + ko]);
            bfr[i] = *reinterpret_cast<const bf16x8*>(&Bs[(wc * 64 + i * 16 + rsel) * 32 + ko]);
        }
#pragma unroll
        for (int i = 0; i < 4; i++)
#pragma unroll
            for (int j = 0; j < 4; j++)
                acc[i][j] = __builtin_amdgcn_mfma_f32_16x16x32_bf16(af[i], bfr[j], acc[i][j], 0, 0, 0);
        __syncthreads();
    }

#pragma unroll
    for (int j = 0; j < 4; j++) {
        int col = n0 + wc * 64 + j * 16 + rsel;
        float bv = (MODE == 3) ? ((n0 < 256) ? bias[col] : bias2[col - 256]) : bias[col];
#pragma unroll
        for (int i = 0; i < 4; i++) {
            int rbase = m0 + wr * 64 + i * 16 + (lane >> 4) * 4;
#pragma unroll
            for (int r2 = 0; r2 < 4; r2++) {
                int gm = rbase + r2;
                float v = acc[i][j][r2] + bv;
                if (MODE == 2) v = fmaxf(v, 0.f);
                if (MODE == 0) ((float*)Cv)[(size_t)gm * N + col] = v;
                else if (MODE == 1 || MODE == 2) ((u16*)Cv)[(size_t)gm * N + col] = bf16_rne(v);
                else {
                    if (n0 < 256) ((float*)Cv)[(size_t)gm * 256 + col] = v;
                    else          ((float*)C2v)[(size_t)gm * 128 + col - 256] = v;
                }
            }
        }
    }
}

// ---------------------------------------------------------------------------
// Multi-scale deformable sampling with INLINE softmax over the 16 logits.
// value bf16; 4 threads per (b,s,h), 8 channels each. Output bf16.
// XCD-chunk swizzle: contiguous token ranges per XCD -> value stays L2-resident.
// Grid is fixed: 3324 blocks of 256 (Q=415, R=4 bijective map).
// ---------------------------------------------------------------------------
__global__ __launch_bounds__(256) void msdeform_kernel(
    const u16* __restrict__ value, const float* __restrict__ off,
    const float* __restrict__ logits, const float* __restrict__ ref,
    u16* __restrict__ out)
{
    const int total = MTOT * NH * 4;
    const int Q = 415, R = 4;
    int bid = blockIdx.x;
    int xcd = bid & 7, cidx = bid >> 3;
    int wg = (xcd < R ? xcd * (Q + 1) : R * (Q + 1) + (xcd - R) * Q) + cidx;
    int t = wg * 256 + (int)threadIdx.x;
    if (t >= total) return;
    int c8 = t & 3;          // 8-channel group
    int h  = (t >> 2) & 7;
    int bs = t >> 5;
    int b  = (bs >= S_TOK) ? 1 : 0;

    const int Ws[4] = {100, 50, 25, 13};
    const int Hs[4] = {100, 50, 25, 13};
    const int st[4] = {0, 10000, 12500, 13125};

    const float* offp = off    + ((size_t)bs * NH + h) * 32;
    const float* lgp  = logits + ((size_t)bs * NH + h) * 16;
    const float* refp = ref    + (size_t)bs * NL * 2;

    // inline softmax over 16 logits
    float lw[16];
    {
        float4 a0 = ((const float4*)lgp)[0];
        float4 a1 = ((const float4*)lgp)[1];
        float4 a2 = ((const float4*)lgp)[2];
        float4 a3 = ((const float4*)lgp)[3];
        lw[0]=a0.x; lw[1]=a0.y; lw[2]=a0.z; lw[3]=a0.w;
        lw[4]=a1.x; lw[5]=a1.y; lw[6]=a1.z; lw[7]=a1.w;
        lw[8]=a2.x; lw[9]=a2.y; lw[10]=a2.z; lw[11]=a2.w;
        lw[12]=a3.x; lw[13]=a3.y; lw[14]=a3.z; lw[15]=a3.w;
        float mx = lw[0];
#pragma unroll
        for (int i = 1; i < 16; i++) mx = fmaxf(mx, lw[i]);
        float s = 0.f;
#pragma unroll
        for (int i = 0; i < 16; i++) { lw[i] = __expf(lw[i] - mx); s += lw[i]; }
        float inv = 1.f / s;
#pragma unroll
        for (int i = 0; i < 16; i++) lw[i] *= inv;
    }

    float acc[8] = {};

#pragma unroll
    for (int l = 0; l < NL; l++) {
        const int W = Ws[l], H = Hs[l];
        const u16* vbase = value + ((size_t)b * S_TOK + st[l]) * D_MODEL + h * HD + c8 * 8;
        const float fW = (float)W, fH = (float)H;
        // x = rx*W - 0.5 + ox ; y = ry*H - 0.5 + oy
        const float rxw = fmaf(refp[l * 2 + 0], fW, -0.5f);
        const float ryh = fmaf(refp[l * 2 + 1], fH, -0.5f);
#pragma unroll
        for (int p = 0; p < NP; p++) {
            float x = rxw + offp[l * 8 + p * 2 + 0];
            float y = ryh + offp[l * 8 + p * 2 + 1];
            float a = lw[l * 4 + p];
            float x0f = floorf(x), y0f = floorf(y);
            float wx1 = x - x0f, wy1 = y - y0f;
            float wx0 = 1.f - wx1, wy0 = 1.f - wy1;
            int ix0 = (int)x0f, iy0 = (int)y0f;
#pragma unroll
            for (int dy = 0; dy < 2; dy++) {
                int yi = iy0 + dy;
                if (yi < 0 || yi >= H) continue;
                float wy = dy ? wy1 : wy0;
#pragma unroll
                for (int dx = 0; dx < 2; dx++) {
                    int xi = ix0 + dx;
                    if (xi < 0 || xi >= W) continue;
                    float wgt = (dx ? wx1 : wx0) * wy * a;
                    uint4 gv = *(const uint4*)(vbase + (size_t)(yi * W + xi) * D_MODEL);
                    union { uint32_t q; float f; } lo, hi;
                    lo.q = gv.x << 16; hi.q = gv.x & 0xffff0000u;
                    acc[0] = fmaf(lo.f, wgt, acc[0]); acc[1] = fmaf(hi.f, wgt, acc[1]);
                    lo.q = gv.y << 16; hi.q = gv.y & 0xffff0000u;
                    acc[2] = fmaf(lo.f, wgt, acc[2]); acc[3] = fmaf(hi.f, wgt, acc[3]);
                    lo.q = gv.z << 16; hi.q = gv.z & 0xffff0000u;
                    acc[4] = fmaf(lo.f, wgt, acc[4]); acc[5] = fmaf(hi.f, wgt, acc[5]);
                    lo.q = gv.w << 16; hi.q = gv.w & 0xffff0000u;
                    acc[6] = fmaf(lo.f, wgt, acc[6]); acc[7] = fmaf(hi.f, wgt, acc[7]);
                }
            }
        }
    }
    uint4 o;
    o.x = ((uint32_t)bf16_rne(acc[1]) << 16) | bf16_rne(acc[0]);
    o.y = ((uint32_t)bf16_rne(acc[3]) << 16) | bf16_rne(acc[2]);
    o.z = ((uint32_t)bf16_rne(acc[5]) << 16) | bf16_rne(acc[4]);
    o.w = ((uint32_t)bf16_rne(acc[7]) << 16) | bf16_rne(acc[6]);
    ((uint4*)out)[((size_t)bs * NH + h) * 4 + c8] = o;
}

// ---------------------------------------------------------------------------
__global__ __launch_bounds__(256) void add_ln1_kernel(
    const float* __restrict__ xres, const float* __restrict__ x2,
    const float* __restrict__ g, const float* __restrict__ be,
    float* __restrict__ outf, u16* __restrict__ outb)
{
    int row = blockIdx.x * 4 + (threadIdx.x >> 6);
    int lane = threadIdx.x & 63;
    if (row >= MTOT) return;
    float4 v = ((const float4*)(xres + (size_t)row * D_MODEL))[lane];
    float4 w = ((const float4*)(x2   + (size_t)row * D_MODEL))[lane];
    v.x += w.x; v.y += w.y; v.z += w.z; v.w += w.w;
    float sum = v.x + v.y + v.z + v.w;
    float sq  = v.x * v.x + v.y * v.y + v.z * v.z + v.w * v.w;
#pragma unroll
    for (int m = 32; m; m >>= 1) { sum += __shfl_xor(sum, m, 64); sq += __shfl_xor(sq, m, 64); }
    float mean = sum * (1.f / D_MODEL);
    float var  = sq * (1.f / D_MODEL) - mean * mean;
    float inv = rsqrtf(var + 1e-5f);
    int cb = lane * 4;
    float4 o;
    o.x = (v.x - mean) * inv * g[cb + 0] + be[cb + 0];
    o.y = (v.y - mean) * inv * g[cb + 1] + be[cb + 1];
    o.z = (v.z - mean) * inv * g[cb + 2] + be[cb + 2];
    o.w = (v.w - mean) * inv * g[cb + 3] + be[cb + 3];
    ((float4*)(outf + (size_t)row * D_MODEL))[lane] = o;
    ushort4 ob;
    ob.x = bf16_rne(o.x); ob.y = bf16_rne(o.y); ob.z = bf16_rne(o.z); ob.w = bf16_rne(o.w);
    ((ushort4*)(outb + (size_t)row * D_MODEL))[lane] = ob;
}

__global__ __launch_bounds__(256) void add_ln2_kernel(
    const float* __restrict__ xres, const float* __restrict__ x2,
    const float* __restrict__ g, const float* __restrict__ be,
    const float* __restrict__ pos,
    float* __restrict__ outf, u16* __restrict__ outXb, u16* __restrict__ outQb)
{
    int row = blockIdx.x * 4 + (threadIdx.x >> 6);
    int lane = threadIdx.x & 63;
    if (row >= MTOT) return;
    float4 v = ((const float4*)(xres + (size_t)row * D_MODEL))[lane];
    float4 w = ((const float4*)(x2   + (size_t)row * D_MODEL))[lane];
    v.x += w.x; v.y += w.y; v.z += w.z; v.w += w.w;
    float sum = v.x + v.y + v.z + v.w;
    float sq  = v.x * v.x + v.y * v.y + v.z * v.z + v.w * v.w;
#pragma unroll
    for (int m = 32; m; m >>= 1) { sum += __shfl_xor(sum, m, 64); sq += __shfl_xor(sq, m, 64); }
    float mean = sum * (1.f / D_MODEL);
    float var  = sq * (1.f / D_MODEL) - mean * mean;
    float inv = rsqrtf(var + 1e-5f);
    int cb = lane * 4;
    float4 o;
    o.x = (v.x - mean) * inv * g[cb + 0] + be[cb + 0];
    o.y = (v.y - mean) * inv * g[cb + 1] + be[cb + 1];
    o.z = (v.z - mean) * inv * g[cb + 2] + be[cb + 2];
    o.w = (v.w - mean) * inv * g[cb + 3] + be[cb + 3];
    ((float4*)(outf + (size_t)row * D_MODEL))[lane] = o;
    ushort4 ob;
    ob.x = bf16_rne(o.x); ob.y = bf16_rne(o.y); ob.z = bf16_rne(o.z); ob.w = bf16_rne(o.w);
    ((ushort4*)(outXb + (size_t)row * D_MODEL))[lane] = ob;
    float4 p = ((const float4*)(pos + (size_t)row * D_MODEL))[lane];
    ushort4 qb;
    qb.x = bf16_rne(o.x + p.x); qb.y = bf16_rne(o.y + p.y);
    qb.z = bf16_rne(o.z + p.z); qb.w = bf16_rne(o.w + p.w);
    ((ushort4*)(outQb + (size_t)row * D_MODEL))[lane] = qb;
}

// ---------------------------------------------------------------------------
extern "C" void kernel_launch(void* const* d_in, const int* in_sizes, int n_in,
                              void* d_out, int out_size, void* d_ws, size_t ws_size,
                              hipStream_t stream)
{
    const float* src    = (const float*)d_in[0];
    const float* pos    = (const float*)d_in[1];
    const float* vr     = (const float*)d_in[2];
    const float* W_off  = (const float*)d_in[3];
    const float* b_off  = (const float*)d_in[4];
    const float* W_attn = (const float*)d_in[5];
    const float* b_attn = (const float*)d_in[6];
    const float* W_val  = (const float*)d_in[7];
    const float* b_val  = (const float*)d_in[8];
    const float* W_out  = (const float*)d_in[9];
    const float* b_out  = (const float*)d_in[10];
    const float* g1     = (const float*)d_in[11];
    const float* be1    = (const float*)d_in[12];
    const float* W_ff1  = (const float*)d_in[13];
    const float* b_ff1  = (const float*)d_in[14];
    const float* W_ff2  = (const float*)d_in[15];
    const float* b_ff2  = (const float*)d_in[16];
    const float* g2     = (const float*)d_in[17];
    const float* be2    = (const float*)d_in[18];
    float* out = (float*)d_out;

    uint8_t* wp = (uint8_t*)d_ws;
    auto alloc = [&](size_t bytes) { uint8_t* p = wp; wp += (bytes + 255) & ~(size_t)255; return p; };
    float* refb   = (float*)alloc((size_t)MTOT * 8 * 4);
    float* Ybuf   = (float*)alloc((size_t)MPAD * 256 * 4);
    float* Xf     = (float*)alloc((size_t)MPAD * 256 * 4);  // dead during FFN -> aliased by ffb16
    float* offb   = (float*)alloc((size_t)MPAD * 256 * 4);  // off -> src2 -> ff2 out
    float* attb   = (float*)alloc((size_t)MPAD * 128 * 4);
    u16*   valb16 = (u16*)alloc((size_t)MPAD * 256 * 2);
    uint8_t* slabB = alloc((size_t)MPAD * 256 * 2);         // Xb16 / samb16
    uint8_t* slabC = alloc((size_t)MPAD * 256 * 2);         // Qb16 / Yb16
    u16* Wt = (u16*)alloc((size_t)NLAYERS * WT_L * 2);

    u16* Xb16   = (u16*)slabB;
    u16* samb16 = (u16*)slabB;
    u16* Qb16   = (u16*)slabC;
    u16* Yb16   = (u16*)slabC;
    u16* ffb16  = (u16*)Xf;   // 13312*1024*2 == MPAD*256*4 bytes exactly

    const int GY = MPAD / 128;   // 208
    const int CHUNK = 13312;     // 104 * 128
    const int MSD_BLOCKS = (MTOT * NH * 4 + 255) / 256;  // 3324

    wprep_kernel<<<(NLAYERS * WT_L + 255) / 256, 256, 0, stream>>>(
        W_val, W_off, W_attn, W_out, W_ff1, W_ff2, Wt);
    refpoints_kernel<<<(MTOT + 255) / 256, 256, 0, stream>>>(vr, refb);
    conv0_kernel<<<(MTOT * 64 + 255) / 256, 256, 0, stream>>>(src, pos, Xb16, Qb16);

    for (int l = 0; l < NLAYERS; l++) {
        const float* Xres = (l == 0) ? src : Xf;
        const u16* Wl = Wt + (size_t)l * WT_L;

        // off|attn = Q @ [Wo|Wa] + [bo|ba]   (split f32 out)
        gemm_bf16<3><<<dim3(3, GY), 256, 0, stream>>>(
            Qb16, Wl + WT_OA2, b_off + l * 256, b_attn + l * 128, offb, attb, 384, 256);
        // value = X @ Wv + bv  (bf16 out)
        gemm_bf16<1><<<dim3(2, GY), 256, 0, stream>>>(
            Xb16, Wl + WT_OV, b_val + l * D_MODEL, nullptr, valb16, nullptr, 256, 256);
        // sampled -> samb16 (overwrites dead Xb16); softmax fused inside
        msdeform_kernel<<<MSD_BLOCKS, 256, 0, stream>>>(
            valb16, offb, attb, refb, samb16);
        // src2 = sampled @ W_out + b_out -> offb (off values dead)
        gemm_bf16<0><<<dim3(2, GY), 256, 0, stream>>>(
            samb16, Wl + WT_OOUT, b_out + l * D_MODEL, nullptr, offb, nullptr, 256, 256);
        // Y = LN(X + src2) -> Ybuf f32, Yb16 (overwrites dead Qb16)
        add_ln1_kernel<<<MTOT / 4, 256, 0, stream>>>(
            Xres, offb, g1 + l * D_MODEL, be1 + l * D_MODEL, Ybuf, Yb16);
        // FFN: 2 chunks; ff1 bf16+relu into ffb16 (aliases dead Xf), ff2 f32 into offb
        for (int r0 = 0; r0 < MPAD; r0 += CHUNK) {
            gemm_bf16<2><<<dim3(8, CHUNK / 128), 256, 0, stream>>>(
                Yb16 + (size_t)r0 * 256, Wl + WT_OF1, b_ff1 + l * DFF, nullptr,
                ffb16, nullptr, 1024, 256);
            gemm_bf16<0><<<dim3(2, CHUNK / 128), 256, 0, stream>>>(
                ffb16, Wl + WT_OF2, b_ff2 + l * D_MODEL, nullptr,
                offb + (size_t)r0 * 256, nullptr, 256, 1024);
        }
        // X' = LN(Y + ff) -> dst f32, bf16 X', bf16 (X'+pos)
        float* dst = (l == NLAYERS - 1) ? out : Xf;
        add_ln2_kernel<<<MTOT / 4, 256, 0, stream>>>(
            Ybuf, offb, g2 + l * D_MODEL, be2 + l * D_MODEL, pos, dst, Xb16, Qb16);
    }
}

// Round 5
// 1269.631 us; speedup vs baseline: 4.4567x; 1.0889x over previous
//
#include <hip/hip_runtime.h>
#include <math.h>
#include <stdint.h>

#define D_MODEL 256
#define NH 8
#define HD 32
#define NL 4
#define NP 4
#define DFF 1024
#define NLAYERS 6
#define BS 2
#define S_TOK 13294
#define MTOT (BS * S_TOK)   // 26588
#define MPAD 26624          // 208 * 128

typedef unsigned short u16;
typedef __attribute__((ext_vector_type(8))) __bf16 bf16x8;
typedef __attribute__((ext_vector_type(4))) float f32x4;

#define AS1 __attribute__((address_space(1)))
#define AS3 __attribute__((address_space(3)))

__device__ inline u16 bf16_rne(float f) {
    union { float f; uint32_t u; } v; v.f = f;
    uint32_t u = v.u;
    return (u16)((u + 0x7FFFu + ((u >> 16) & 1u)) >> 16);
}

// ---------------------------------------------------------------------------
// Weight prep: bf16, transposed to [N][K]. Per-layer segments (elements):
//   [QAV: (Wo|Wa|Wv) 640*256][OUT: 256*256][F1: 1024*256][F2: 256*1024]
// ---------------------------------------------------------------------------
#define WT_L 753664
#define WT_OA2 0
#define WT_OV 98304
#define WT_OOUT 163840
#define WT_OF1 229376
#define WT_OF2 491520

__global__ void wprep_kernel(const float* __restrict__ Wv, const float* __restrict__ Wo,
                             const float* __restrict__ Wa, const float* __restrict__ Wout,
                             const float* __restrict__ Wf1, const float* __restrict__ Wf2,
                             u16* __restrict__ dst)
{
    int idx = blockIdx.x * blockDim.x + threadIdx.x;
    if (idx >= NLAYERS * WT_L) return;
    int l = idx / WT_L;
    int r = idx - l * WT_L;
    float val;
    if (r < WT_OV) {                       // cols 0-255 = Wo, 256-383 = Wa
        int n = r >> 8, k = r & 255;
        if (n < 256) val = Wo[(size_t)l * 65536 + k * 256 + n];
        else         val = Wa[(size_t)l * 32768 + k * 128 + (n - 256)];
    } else if (r < WT_OOUT) {              // 384-639 = Wv
        int sr = r - WT_OV; int n = sr >> 8, k = sr & 255;
        val = Wv[(size_t)l * 65536 + k * 256 + n];
    } else if (r < WT_OF1) {
        int sr = r - WT_OOUT; int n = sr >> 8, k = sr & 255;
        val = Wout[(size_t)l * 65536 + k * 256 + n];
    } else if (r < WT_OF2) {
        int sr = r - WT_OF1; int n = sr >> 8, k = sr & 255;       // N=1024, K=256
        val = Wf1[(size_t)l * 262144 + k * 1024 + n];
    } else {
        int sr = r - WT_OF2; int n = sr >> 10, k = sr & 1023;     // N=256, K=1024
        val = Wf2[(size_t)l * 262144 + k * 256 + n];
    }
    dst[(size_t)l * WT_L + r] = bf16_rne(val);
}

// ---------------------------------------------------------------------------
__global__ void refpoints_kernel(const float* __restrict__ vr, float* __restrict__ ref)
{
    int t = blockIdx.x * blockDim.x + threadIdx.x;
    if (t >= MTOT) return;
    int b = t / S_TOK;
    int s = t - b * S_TOK;
    int lvl, W, H, start;
    if (s < 10000)      { lvl = 0; W = 100; H = 100; start = 0; }
    else if (s < 12500) { lvl = 1; W = 50;  H = 50;  start = 10000; }
    else if (s < 13125) { lvl = 2; W = 25;  H = 25;  start = 12500; }
    else                { lvl = 3; W = 13;  H = 13;  start = 13125; }
    int wi = s - start;
    int y = wi / W;
    int x = wi - y * W;
    float rx = (x + 0.5f) / (vr[(b * NL + lvl) * 2 + 0] * (float)W);
    float ry = (y + 0.5f) / (vr[(b * NL + lvl) * 2 + 1] * (float)H);
#pragma unroll
    for (int l2 = 0; l2 < NL; l2++) {
        ref[((size_t)t * NL + l2) * 2 + 0] = rx * vr[(b * NL + l2) * 2 + 0];
        ref[((size_t)t * NL + l2) * 2 + 1] = ry * vr[(b * NL + l2) * 2 + 1];
    }
}

// ---------------------------------------------------------------------------
__global__ void conv0_kernel(const float* __restrict__ src, const float* __restrict__ pos,
                             u16* __restrict__ Xb, u16* __restrict__ Qb)
{
    int t = blockIdx.x * blockDim.x + threadIdx.x;
    if (t >= MTOT * 64) return;
    float4 s = ((const float4*)src)[t];
    float4 p = ((const float4*)pos)[t];
    ushort4 a, q;
    a.x = bf16_rne(s.x); a.y = bf16_rne(s.y); a.z = bf16_rne(s.z); a.w = bf16_rne(s.w);
    q.x = bf16_rne(s.x + p.x); q.y = bf16_rne(s.y + p.y);
    q.z = bf16_rne(s.z + p.z); q.w = bf16_rne(s.w + p.w);
    ((ushort4*)Xb)[t] = a;
    ((ushort4*)Qb)[t] = q;
}

// ---------------------------------------------------------------------------
// 128x128 BF16 MFMA GEMM.
// MODE 2 (ff1): C0 = bf16(relu(A@Bt^T + bias)), stride N.
// MODE 4 (QAV fused, N=640): block-uniform by n0:
//   n0<256  : A=Aq, f32 C0 stride 256, bias
//   n0==256 : A=Aq, f32 C1 stride 128, bias2 (cols-256)
//   n0>=384 : A=Ax, bf16 C2 stride 256, bias3 (cols-384)
// XCD-chunk bijective block swizzle (grid % 8 handled via remainder formula).
// ---------------------------------------------------------------------------
template<int MODE>
__global__ __launch_bounds__(256) void gemm_bf16(
    const u16* __restrict__ Aq, const u16* __restrict__ Ax,
    const u16* __restrict__ Bt,
    const float* __restrict__ bias, const float* __restrict__ bias2,
    const float* __restrict__ bias3,
    void* __restrict__ C0, void* __restrict__ C1, void* __restrict__ C2,
    int N, int K)
{
    __shared__ __align__(16) u16 As[128 * 32];
    __shared__ __align__(16) u16 Bs[128 * 32];

    const int tid = threadIdx.x;
    const int wid = tid >> 6;
    const int lane = tid & 63;

    const int nwg = gridDim.x * gridDim.y;
    const int bid = blockIdx.y * gridDim.x + blockIdx.x;
    const int q = nwg >> 3, rr = nwg & 7;
    const int xcd = bid & 7, cidx = bid >> 3;
    const int wg = (xcd < rr ? xcd * (q + 1) : rr * (q + 1) + (xcd - rr) * q) + cidx;
    const int m0 = (wg / gridDim.x) * 128;
    const int n0 = (wg % gridDim.x) * 128;
    const int wr = wid >> 1, wc = wid & 1;

    f32x4 acc[4][4] = {};

    const u16* Ause = (MODE == 4 && n0 >= 384) ? Ax : Aq;
    const u16* a0 = Ause + (size_t)(m0 + (tid >> 2)) * K + (tid & 3) * 8;
    const u16* b0 = Bt + (size_t)(n0 + (tid >> 2)) * K + (tid & 3) * 8;
    u16* asb = As + wid * 512;
    u16* bsb = Bs + wid * 512;

    const int ko = (lane >> 4) * 8;
    const int rsel = lane & 15;

    for (int k0 = 0; k0 < K; k0 += 32) {
        __builtin_amdgcn_global_load_lds((AS1 void*)(a0 + k0), (AS3 void*)(asb), 16, 0, 0);
        __builtin_amdgcn_global_load_lds((AS1 void*)(a0 + (size_t)64 * K + k0),
                                         (AS3 void*)(asb + 2048), 16, 0, 0);
        __builtin_amdgcn_global_load_lds((AS1 void*)(b0 + k0), (AS3 void*)(bsb), 16, 0, 0);
        __builtin_amdgcn_global_load_lds((AS1 void*)(b0 + (size_t)64 * K + k0),
                                         (AS3 void*)(bsb + 2048), 16, 0, 0);
        __syncthreads();

        bf16x8 af[4], bfr[4];
#pragma unroll
        for (int i = 0; i < 4; i++) {
            af[i]  = *reinterpret_cast<const bf16x8*>(&As[(wr * 64 + i * 16 + rsel) * 32 + ko]);
            bfr[i] = *reinterpret_cast<const bf16x8*>(&Bs[(wc * 64 + i * 16 + rsel) * 32 + ko]);
        }
#pragma unroll
        for (int i = 0; i < 4; i++)
#pragma unroll
            for (int j = 0; j < 4; j++)
                acc[i][j] = __builtin_amdgcn_mfma_f32_16x16x32_bf16(af[i], bfr[j], acc[i][j], 0, 0, 0);
        __syncthreads();
    }

#pragma unroll
    for (int j = 0; j < 4; j++) {
        int col = n0 + wc * 64 + j * 16 + rsel;
        float bv;
        if (MODE == 4) bv = (n0 < 256) ? bias[col] : (n0 == 256) ? bias2[col - 256] : bias3[col - 384];
        else bv = bias[col];
#pragma unroll
        for (int i = 0; i < 4; i++) {
            int rbase = m0 + wr * 64 + i * 16 + (lane >> 4) * 4;
#pragma unroll
            for (int r2 = 0; r2 < 4; r2++) {
                int gm = rbase + r2;
                float v = acc[i][j][r2] + bv;
                if (MODE == 2) {
                    v = fmaxf(v, 0.f);
                    ((u16*)C0)[(size_t)gm * N + col] = bf16_rne(v);
                } else {
                    if (n0 < 256)       ((float*)C0)[(size_t)gm * 256 + col] = v;
                    else if (n0 == 256) ((float*)C1)[(size_t)gm * 128 + col - 256] = v;
                    else                ((u16*)C2)[(size_t)gm * 256 + col - 384] = bf16_rne(v);
                }
            }
        }
    }
}

// ---------------------------------------------------------------------------
// BM=64 x BN=256 GEMM with fused residual-add + LayerNorm epilogue.
// 256 threads = 4 waves, wave wc owns cols [wc*64, wc*64+64), rows 0..63.
// LNMODE 1 (W_out+LN1): y = LN(Xres + A@Bt^T + bias); writes dstf f32 + dstb bf16.
// LNMODE 2 (ff2+LN2):   additionally writes dstq = bf16(y + pos).
// Xres/pos reads guarded to < MTOT (src/pos are unpadded inputs).
// Writes guarded to < Mguard (MTOT when dstf == d_out, else MPAD).
// ---------------------------------------------------------------------------
template<int LNMODE>
__global__ __launch_bounds__(256) void gemm_ln(
    const u16* __restrict__ A, const u16* __restrict__ Bt,
    const float* __restrict__ bias,
    const float* __restrict__ Xres, const float* __restrict__ g,
    const float* __restrict__ be, const float* __restrict__ pos,
    float* __restrict__ dstf, u16* __restrict__ dstb, u16* __restrict__ dstq,
    int K, int Mguard)
{
    __shared__ __align__(16) u16 As[64 * 32];
    __shared__ __align__(16) u16 Bs[256 * 32];
    __shared__ float redS[64][4], redQ[64][4], mrow[64], irow[64];

    const int tid = threadIdx.x;
    const int wc = tid >> 6;
    const int lane = tid & 63;

    const int nwg = gridDim.x;          // 416, % 8 == 0
    const int q = nwg >> 3;
    const int wg = (blockIdx.x & 7) * q + (blockIdx.x >> 3);
    const int m0 = wg * 64;

    f32x4 acc[4][4] = {};

    const u16* a0 = A + (size_t)(m0 + (tid >> 2)) * K + (tid & 3) * 8;
    const u16* b0 = Bt + (size_t)(tid >> 2) * K + (tid & 3) * 8;
    u16* asb = As + wc * 512;
    u16* bsb = Bs + wc * 512;

    const int gsel = lane >> 4;
    const int rsel = lane & 15;
    const int ko = gsel * 8;

    for (int k0 = 0; k0 < K; k0 += 32) {
        __builtin_amdgcn_global_load_lds((AS1 void*)(a0 + k0), (AS3 void*)(asb), 16, 0, 0);
#pragma unroll
        for (int ii = 0; ii < 4; ii++)
            __builtin_amdgcn_global_load_lds((AS1 void*)(b0 + (size_t)ii * 64 * K + k0),
                                             (AS3 void*)(bsb + ii * 2048), 16, 0, 0);
        __syncthreads();

        bf16x8 af[4], bfr[4];
#pragma unroll
        for (int i = 0; i < 4; i++) {
            af[i]  = *reinterpret_cast<const bf16x8*>(&As[(i * 16 + rsel) * 32 + ko]);
            bfr[i] = *reinterpret_cast<const bf16x8*>(&Bs[(wc * 64 + i * 16 + rsel) * 32 + ko]);
        }
#pragma unroll
        for (int i = 0; i < 4; i++)
#pragma unroll
            for (int j = 0; j < 4; j++)
                acc[i][j] = __builtin_amdgcn_mfma_f32_16x16x32_bf16(af[i], bfr[j], acc[i][j], 0, 0, 0);
        __syncthreads();
    }

    float bias_j[4], g_j[4], be_j[4];
#pragma unroll
    for (int j = 0; j < 4; j++) {
        int col = wc * 64 + j * 16 + rsel;
        bias_j[j] = bias[col]; g_j[j] = g[col]; be_j[j] = be[col];
    }

    // fold bias + residual into acc; butterfly row-sums over the 16 rsel lanes
#pragma unroll
    for (int i = 0; i < 4; i++)
#pragma unroll
    for (int r = 0; r < 4; r++) {
        int row = i * 16 + gsel * 4 + r;
        int grow = m0 + row;
        float s = 0.f, qq = 0.f;
#pragma unroll
        for (int j = 0; j < 4; j++) {
            int col = wc * 64 + j * 16 + rsel;
            float xr = (grow < MTOT) ? Xres[(size_t)grow * 256 + col] : 0.f;
            float v = acc[i][j][r] + bias_j[j] + xr;
            acc[i][j][r] = v;
            s += v; qq += v * v;
        }
#pragma unroll
        for (int m = 1; m <= 8; m <<= 1) {
            s += __shfl_xor(s, m, 64);
            qq += __shfl_xor(qq, m, 64);
        }
        if (rsel == 0) { redS[row][wc] = s; redQ[row][wc] = qq; }
    }
    __syncthreads();
    if (tid < 64) {
        float s  = redS[tid][0] + redS[tid][1] + redS[tid][2] + redS[tid][3];
        float qq = redQ[tid][0] + redQ[tid][1] + redQ[tid][2] + redQ[tid][3];
        float mean = s * (1.f / 256.f);
        float var  = qq * (1.f / 256.f) - mean * mean;
        mrow[tid] = mean;
        irow[tid] = rsqrtf(var + 1e-5f);
    }
    __syncthreads();

#pragma unroll
    for (int i = 0; i < 4; i++)
#pragma unroll
    for (int r = 0; r < 4; r++) {
        int row = i * 16 + gsel * 4 + r;
        int grow = m0 + row;
        if (grow >= Mguard) continue;
        float mean = mrow[row], inv = irow[row];
#pragma unroll
        for (int j = 0; j < 4; j++) {
            int col = wc * 64 + j * 16 + rsel;
            float y = (acc[i][j][r] - mean) * inv * g_j[j] + be_j[j];
            dstf[(size_t)grow * 256 + col] = y;
            dstb[(size_t)grow * 256 + col] = bf16_rne(y);
            if (LNMODE == 2) {
                float pv = (grow < MTOT) ? pos[(size_t)grow * 256 + col] : 0.f;
                dstq[(size_t)grow * 256 + col] = bf16_rne(y + pv);
            }
        }
    }
}

// ---------------------------------------------------------------------------
// Multi-scale deformable sampling with inline softmax; value bf16,
// 4 threads per (b,s,h), 8 channels each; XCD-chunk swizzle.
// ---------------------------------------------------------------------------
__global__ __launch_bounds__(256) void msdeform_kernel(
    const u16* __restrict__ value, const float* __restrict__ off,
    const float* __restrict__ logits, const float* __restrict__ ref,
    u16* __restrict__ out)
{
    const int total = MTOT * NH * 4;
    const int Q = 415, R = 4;
    int bid = blockIdx.x;
    int xcd = bid & 7, cidx = bid >> 3;
    int wg = (xcd < R ? xcd * (Q + 1) : R * (Q + 1) + (xcd - R) * Q) + cidx;
    int t = wg * 256 + (int)threadIdx.x;
    if (t >= total) return;
    int c8 = t & 3;
    int h  = (t >> 2) & 7;
    int bs = t >> 5;
    int b  = (bs >= S_TOK) ? 1 : 0;

    const int Ws[4] = {100, 50, 25, 13};
    const int Hs[4] = {100, 50, 25, 13};
    const int st[4] = {0, 10000, 12500, 13125};

    const float* offp = off    + ((size_t)bs * NH + h) * 32;
    const float* lgp  = logits + ((size_t)bs * NH + h) * 16;
    const float* refp = ref    + (size_t)bs * NL * 2;

    float lw[16];
    {
        float4 a0 = ((const float4*)lgp)[0];
        float4 a1 = ((const float4*)lgp)[1];
        float4 a2 = ((const float4*)lgp)[2];
        float4 a3 = ((const float4*)lgp)[3];
        lw[0]=a0.x; lw[1]=a0.y; lw[2]=a0.z; lw[3]=a0.w;
        lw[4]=a1.x; lw[5]=a1.y; lw[6]=a1.z; lw[7]=a1.w;
        lw[8]=a2.x; lw[9]=a2.y; lw[10]=a2.z; lw[11]=a2.w;
        lw[12]=a3.x; lw[13]=a3.y; lw[14]=a3.z; lw[15]=a3.w;
        float mx = lw[0];
#pragma unroll
        for (int i = 1; i < 16; i++) mx = fmaxf(mx, lw[i]);
        float s = 0.f;
#pragma unroll
        for (int i = 0; i < 16; i++) { lw[i] = __expf(lw[i] - mx); s += lw[i]; }
        float inv = 1.f / s;
#pragma unroll
        for (int i = 0; i < 16; i++) lw[i] *= inv;
    }

    float acc[8] = {};

#pragma unroll
    for (int l = 0; l < NL; l++) {
        const int W = Ws[l], H = Hs[l];
        const u16* vbase = value + ((size_t)b * S_TOK + st[l]) * D_MODEL + h * HD + c8 * 8;
        const float fW = (float)W, fH = (float)H;
        const float rxw = fmaf(refp[l * 2 + 0], fW, -0.5f);
        const float ryh = fmaf(refp[l * 2 + 1], fH, -0.5f);
#pragma unroll
        for (int p = 0; p < NP; p++) {
            float x = rxw + offp[l * 8 + p * 2 + 0];
            float y = ryh + offp[l * 8 + p * 2 + 1];
            float a = lw[l * 4 + p];
            float x0f = floorf(x), y0f = floorf(y);
            float wx1 = x - x0f, wy1 = y - y0f;
            float wx0 = 1.f - wx1, wy0 = 1.f - wy1;
            int ix0 = (int)x0f, iy0 = (int)y0f;
#pragma unroll
            for (int dy = 0; dy < 2; dy++) {
                int yi = iy0 + dy;
                if (yi < 0 || yi >= H) continue;
                float wy = dy ? wy1 : wy0;
#pragma unroll
                for (int dx = 0; dx < 2; dx++) {
                    int xi = ix0 + dx;
                    if (xi < 0 || xi >= W) continue;
                    float wgt = (dx ? wx1 : wx0) * wy * a;
                    uint4 gv = *(const uint4*)(vbase + (size_t)(yi * W + xi) * D_MODEL);
                    union { uint32_t q; float f; } lo, hi;
                    lo.q = gv.x << 16; hi.q = gv.x & 0xffff0000u;
                    acc[0] = fmaf(lo.f, wgt, acc[0]); acc[1] = fmaf(hi.f, wgt, acc[1]);
                    lo.q = gv.y << 16; hi.q = gv.y & 0xffff0000u;
                    acc[2] = fmaf(lo.f, wgt, acc[2]); acc[3] = fmaf(hi.f, wgt, acc[3]);
                    lo.q = gv.z << 16; hi.q = gv.z & 0xffff0000u;
                    acc[4] = fmaf(lo.f, wgt, acc[4]); acc[5] = fmaf(hi.f, wgt, acc[5]);
                    lo.q = gv.w << 16; hi.q = gv.w & 0xffff0000u;
                    acc[6] = fmaf(lo.f, wgt, acc[6]); acc[7] = fmaf(hi.f, wgt, acc[7]);
                }
            }
        }
    }
    uint4 o;
    o.x = ((uint32_t)bf16_rne(acc[1]) << 16) | bf16_rne(acc[0]);
    o.y = ((uint32_t)bf16_rne(acc[3]) << 16) | bf16_rne(acc[2]);
    o.z = ((uint32_t)bf16_rne(acc[5]) << 16) | bf16_rne(acc[4]);
    o.w = ((uint32_t)bf16_rne(acc[7]) << 16) | bf16_rne(acc[6]);
    ((uint4*)out)[((size_t)bs * NH + h) * 4 + c8] = o;
}

// ---------------------------------------------------------------------------
extern "C" void kernel_launch(void* const* d_in, const int* in_sizes, int n_in,
                              void* d_out, int out_size, void* d_ws, size_t ws_size,
                              hipStream_t stream)
{
    const float* src    = (const float*)d_in[0];
    const float* pos    = (const float*)d_in[1];
    const float* vr     = (const float*)d_in[2];
    const float* W_off  = (const float*)d_in[3];
    const float* b_off  = (const float*)d_in[4];
    const float* W_attn = (const float*)d_in[5];
    const float* b_attn = (const float*)d_in[6];
    const float* W_val  = (const float*)d_in[7];
    const float* b_val  = (const float*)d_in[8];
    const float* W_out  = (const float*)d_in[9];
    const float* b_out  = (const float*)d_in[10];
    const float* g1     = (const float*)d_in[11];
    const float* be1    = (const float*)d_in[12];
    const float* W_ff1  = (const float*)d_in[13];
    const float* b_ff1  = (const float*)d_in[14];
    const float* W_ff2  = (const float*)d_in[15];
    const float* b_ff2  = (const float*)d_in[16];
    const float* g2     = (const float*)d_in[17];
    const float* be2    = (const float*)d_in[18];
    float* out = (float*)d_out;

    uint8_t* wp = (uint8_t*)d_ws;
    auto alloc = [&](size_t bytes) { uint8_t* p = wp; wp += (bytes + 255) & ~(size_t)255; return p; };
    float* refb   = (float*)alloc((size_t)MTOT * 8 * 4);
    float* Ybuf   = (float*)alloc((size_t)MPAD * 256 * 4);
    float* Xf     = (float*)alloc((size_t)MPAD * 256 * 4);
    // [offb | attb | valb16] contiguous: all dead during FFN -> aliased by ffb16
    float* offb   = (float*)alloc((size_t)MPAD * 256 * 4);
    float* attb   = (float*)alloc((size_t)MPAD * 128 * 4);
    u16*   valb16 = (u16*)alloc((size_t)MPAD * 256 * 2);
    uint8_t* slabB = alloc((size_t)MPAD * 256 * 2);         // Xb16 / samb16
    uint8_t* slabC = alloc((size_t)MPAD * 256 * 2);         // Qb16 / Yb16
    u16* Wt = (u16*)alloc((size_t)NLAYERS * WT_L * 2);

    u16* Xb16   = (u16*)slabB;
    u16* samb16 = (u16*)slabB;
    u16* Qb16   = (u16*)slabC;
    u16* Yb16   = (u16*)slabC;
    u16* ffb16  = (u16*)offb;   // 27.25 + 13.63 + 13.63 MB == MPAD*1024*2 B exactly

    const int GY = MPAD / 128;            // 208
    const int GLN = MPAD / 64;            // 416
    const int MSD_BLOCKS = (MTOT * NH * 4 + 255) / 256;  // 3324

    wprep_kernel<<<(NLAYERS * WT_L + 255) / 256, 256, 0, stream>>>(
        W_val, W_off, W_attn, W_out, W_ff1, W_ff2, Wt);
    refpoints_kernel<<<(MTOT + 255) / 256, 256, 0, stream>>>(vr, refb);
    conv0_kernel<<<(MTOT * 64 + 255) / 256, 256, 0, stream>>>(src, pos, Xb16, Qb16);

    for (int l = 0; l < NLAYERS; l++) {
        const float* Xres = (l == 0) ? src : Xf;
        const u16* Wl = Wt + (size_t)l * WT_L;

        // off|attn|value fused: Q @ [Wo|Wa] and X @ Wv, one dispatch (N=640)
        gemm_bf16<4><<<dim3(5, GY), 256, 0, stream>>>(
            Qb16, Xb16, Wl + WT_OA2,
            b_off + l * 256, b_attn + l * 128, b_val + l * 256,
            offb, attb, valb16, 640, 256);
        // sampled -> samb16 (overwrites dead Xb16); softmax fused inside
        msdeform_kernel<<<MSD_BLOCKS, 256, 0, stream>>>(
            valb16, offb, attb, refb, samb16);
        // Y = LN(Xres + sampled @ W_out + b_out): fused epilogue
        gemm_ln<1><<<GLN, 256, 0, stream>>>(
            samb16, Wl + WT_OOUT, b_out + l * 256,
            Xres, g1 + l * 256, be1 + l * 256, nullptr,
            Ybuf, Yb16, nullptr, 256, MPAD);
        // ff1: bf16 relu(Y @ Wf1 + b), one dispatch into ffb16 (aliases offb..valb16)
        gemm_bf16<2><<<dim3(8, GY), 256, 0, stream>>>(
            Yb16, nullptr, Wl + WT_OF1, b_ff1 + l * DFF, nullptr, nullptr,
            ffb16, nullptr, nullptr, 1024, 256);
        // X' = LN(Y + ff @ Wf2 + b): fused epilogue, also emits bf16 X' and (X'+pos)
        float* dst = (l == NLAYERS - 1) ? out : Xf;
        int mg = (l == NLAYERS - 1) ? MTOT : MPAD;
        gemm_ln<2><<<GLN, 256, 0, stream>>>(
            ffb16, Wl + WT_OF2, b_ff2 + l * 256,
            Ybuf, g2 + l * 256, be2 + l * 256, pos,
            dst, Xb16, Qb16, 1024, mg);
    }
}